// Round 1
// baseline (664.552 us; speedup 1.0000x reference)
//
#include <hip/hip_runtime.h>
#include <hip/hip_bf16.h>
#include <math.h>

#define THREADS 256

__device__ __forceinline__ float sigmoidf_(float x) { return 1.f / (1.f + expf(-x)); }

struct F8 { float v[8]; };
__device__ __forceinline__ F8 ld8(const float* p) {
    F8 r;
    float4 a = *(const float4*)p;
    float4 b = *(const float4*)(p + 4);
    r.v[0] = a.x; r.v[1] = a.y; r.v[2] = a.z; r.v[3] = a.w;
    r.v[4] = b.x; r.v[5] = b.y; r.v[6] = b.z; r.v[7] = b.w;
    return r;
}

// ------------------------------------------------------------------
// prep: pad/concat weights into Wp[288][256], Wqp[384][128], bpn[256], bpq[128]
// ------------------------------------------------------------------
__global__ void prep_kernel(const float* __restrict__ W_key, const float* __restrict__ W_val,
                            const float* __restrict__ W_q, const float* __restrict__ b_key,
                            const float* __restrict__ b_val, const float* __restrict__ b_q,
                            float* __restrict__ Wp, float* __restrict__ Wqp,
                            float* __restrict__ bpn, float* __restrict__ bpq)
{
    int i = blockIdx.x * THREADS + threadIdx.x;
    const int NW = 288 * 256, NQ = 384 * 128;
    if (i < NW) {
        int k = i >> 8, c = i & 255;
        float v = 0.f;
        if (k < 283) {
            if (c < 100) v = W_key[k * 100 + c];
            else if (c < 228) v = W_val[k * 128 + (c - 100)];
        }
        Wp[i] = v;
    } else if (i < NW + NQ) {
        int j = i - NW;
        int k = j >> 7, c = j & 127;
        Wqp[j] = (c < 100) ? W_q[k * 100 + c] : 0.f;
    } else if (i < NW + NQ + 256) {
        int c = i - NW - NQ;
        bpn[c] = (c < 100) ? b_key[c] : ((c < 228) ? b_val[c - 100] : 0.f);
    } else if (i < NW + NQ + 256 + 128) {
        int c = i - NW - NQ - 256;
        bpq[c] = (c < 100) ? b_q[c] : 0.f;
    }
}

// ------------------------------------------------------------------
// skip features: [N,32], cols 0..26 real, 27..31 zero
// ------------------------------------------------------------------
__global__ void skip_kernel(const float* __restrict__ energy, const float* __restrict__ eta,
                            const float* __restrict__ phi, const float* __restrict__ layer,
                            const float* __restrict__ eta_l, const float* __restrict__ phi_l,
                            const float* __restrict__ ene_l, const float* __restrict__ track,
                            float* __restrict__ skip, int N_)
{
    int n = blockIdx.x * THREADS + threadIdx.x;
    if (n >= N_) return;
    float* o = skip + n * 32;
    o[0] = (logf(energy[n]) - 4.0f) * 0.5f;
    o[1] = eta[n] * (1.f / 1.5f);
    o[2] = phi[n];
    o[3] = layer[n];
#pragma unroll
    for (int j = 0; j < 6; ++j) o[4 + j]  = eta_l[n * 6 + j] * (1.f / 1.5f);
#pragma unroll
    for (int j = 0; j < 6; ++j) o[10 + j] = phi_l[n * 6 + j];
#pragma unroll
    for (int j = 0; j < 6; ++j) o[16 + j] = ene_l[n * 6 + j];
#pragma unroll
    for (int j = 0; j < 5; ++j) o[22 + j] = track[n * 5 + j];
#pragma unroll
    for (int j = 27; j < 32; ++j) o[j] = 0.f;
}

// ------------------------------------------------------------------
// tiled fp32 GEMM, virtual concatenated A.
// MODE 0: A(m,k) = k<256 ? A0[m*256+k] : A1[m*32+(k-256)]   (node_hidden | skip)
// MODE 1: A(m,k) = k<128 ? A0[m*128+k] : A1[m*256+(k-128)]  (particle_hidden | global_rep)
// BM=BN=128, BK=32, block 256, 8x8 micro-tile.
// ------------------------------------------------------------------
template <int MODE>
__global__ __launch_bounds__(256) void gemm_kernel(
    const float* __restrict__ A0, const float* __restrict__ A1,
    const float* __restrict__ W, const float* __restrict__ bias,
    float* __restrict__ C, int M, int Ksz, int ldw, int ldc)
{
    __shared__ float As2[32 * 132];  // [k][m], padded stride 132
    __shared__ float Bs[32 * 128];   // [k][n]
    int tid = threadIdx.x;
    int txn = tid & 15, tym = tid >> 4;
    int row0 = blockIdx.y * 128, col0 = blockIdx.x * 128;
    float acc[8][8] = {};

    for (int kt = 0; kt < Ksz; kt += 32) {
        // A tile: 128 rows x 32 k, float4 along k, store transposed
#pragma unroll
        for (int it = 0; it < 4; ++it) {
            int idx = tid + it * 256;
            int r = idx >> 3, c4 = idx & 7;
            int gm = row0 + r, gk = kt + c4 * 4;
            float4 v = make_float4(0.f, 0.f, 0.f, 0.f);
            if (gm < M) {
                if (MODE == 0)
                    v = (gk < 256) ? *(const float4*)(A0 + gm * 256 + gk)
                                   : *(const float4*)(A1 + gm * 32 + (gk - 256));
                else
                    v = (gk < 128) ? *(const float4*)(A0 + gm * 128 + gk)
                                   : *(const float4*)(A1 + gm * 256 + (gk - 128));
            }
            int kb = c4 * 4;
            As2[(kb + 0) * 132 + r] = v.x;
            As2[(kb + 1) * 132 + r] = v.y;
            As2[(kb + 2) * 132 + r] = v.z;
            As2[(kb + 3) * 132 + r] = v.w;
        }
        // B tile: 32 rows x 128 cols
#pragma unroll
        for (int it = 0; it < 4; ++it) {
            int idx = tid + it * 256;
            int r = idx >> 5, c4 = idx & 31;
            float4 v = *(const float4*)(W + (kt + r) * ldw + col0 + c4 * 4);
            *(float4*)(Bs + r * 128 + c4 * 4) = v;
        }
        __syncthreads();
#pragma unroll
        for (int kk = 0; kk < 32; ++kk) {
            float4 a0 = *(float4*)(As2 + kk * 132 + tym * 8);
            float4 a1 = *(float4*)(As2 + kk * 132 + tym * 8 + 4);
            float4 b0 = *(float4*)(Bs + kk * 128 + txn * 8);
            float4 b1 = *(float4*)(Bs + kk * 128 + txn * 8 + 4);
            float av[8] = {a0.x, a0.y, a0.z, a0.w, a1.x, a1.y, a1.z, a1.w};
            float bv[8] = {b0.x, b0.y, b0.z, b0.w, b1.x, b1.y, b1.z, b1.w};
#pragma unroll
            for (int i = 0; i < 8; ++i)
#pragma unroll
                for (int j = 0; j < 8; ++j) acc[i][j] += av[i] * bv[j];
        }
        __syncthreads();
    }
    float bb[8];
#pragma unroll
    for (int j = 0; j < 8; ++j) bb[j] = bias[col0 + txn * 8 + j];
#pragma unroll
    for (int i = 0; i < 8; ++i) {
        int r = row0 + tym * 8 + i;
        if (r < M) {
            float4 o0 = make_float4(acc[i][0] + bb[0], acc[i][1] + bb[1], acc[i][2] + bb[2], acc[i][3] + bb[3]);
            float4 o1 = make_float4(acc[i][4] + bb[4], acc[i][5] + bb[5], acc[i][6] + bb[6], acc[i][7] + bb[7]);
            *(float4*)(C + r * ldc + col0 + txn * 8) = o0;
            *(float4*)(C + r * ldc + col0 + txn * 8 + 4) = o1;
        }
    }
}

// ------------------------------------------------------------------
// per-edge attention: 16 lanes per edge, dot over 100 (cols 100..111 of Q are 0)
// ------------------------------------------------------------------
__global__ void att_kernel(const int* __restrict__ esrc, const int* __restrict__ edst,
                           const float* __restrict__ C1, const float* __restrict__ Qb,
                           float* __restrict__ att, int E_)
{
    int tid = threadIdx.x;
    int e = blockIdx.x * 16 + (tid >> 4);
    int s = tid & 15;
    float sum = 0.f;
    if (e < E_) {
        const float* kp = C1 + (size_t)esrc[e] * 256;
        const float* qp = Qb + (size_t)edst[e] * 128;
#pragma unroll
        for (int k = 0; k < 112; k += 16) sum += kp[s + k] * qp[s + k];
    }
    sum += __shfl_xor(sum, 1);
    sum += __shfl_xor(sum, 2);
    sum += __shfl_xor(sum, 4);
    sum += __shfl_xor(sum, 8);
    if (e < E_ && s == 0) att[e] = fmaxf(sum * 0.1f, 0.f);
}

// ------------------------------------------------------------------
// CSR build
// ------------------------------------------------------------------
__global__ void zero_ints(int* __restrict__ p, int n)
{
    int i = blockIdx.x * THREADS + threadIdx.x;
    if (i < n) p[i] = 0;
}

__global__ void hist_kernel(const int* __restrict__ dst, int* __restrict__ cnt, int E_)
{
    int i = blockIdx.x * THREADS + threadIdx.x;
    if (i < E_) atomicAdd(&cnt[dst[i]], 1);
}

__global__ void scan_kernel(const int* __restrict__ cnt, int* __restrict__ offb, int P_)
{
    __shared__ int sd[1024];
    __shared__ int carry_s;
    int tid = threadIdx.x;
    if (tid == 0) carry_s = 0;
    __syncthreads();
    int nch = (P_ + 1023) / 1024;
    for (int ch = 0; ch < nch; ++ch) {
        int i = ch * 1024 + tid;
        int v = (i < P_) ? cnt[i] : 0;
        sd[tid] = v;
        __syncthreads();
        int carry = carry_s;
        for (int o = 1; o < 1024; o <<= 1) {
            int t2 = (tid >= o) ? sd[tid - o] : 0;
            __syncthreads();
            sd[tid] += t2;
            __syncthreads();
        }
        if (i < P_) offb[i] = carry + sd[tid] - v;
        __syncthreads();
        if (tid == 0) carry_s = carry + sd[1023];
        __syncthreads();
    }
    if (tid == 0) offb[P_] = carry_s;
}

__global__ void fill_kernel(const int* __restrict__ dst, const int* __restrict__ offb,
                            int* __restrict__ cur, int* __restrict__ eidx, int E_)
{
    int i = blockIdx.x * THREADS + threadIdx.x;
    if (i < E_) {
        int d = dst[i];
        int pos = atomicAdd(&cur[d], 1);
        eidx[offb[d] + pos] = i;
    }
}

// ------------------------------------------------------------------
// gather: one block (128 threads) per particle; acc over its edge list
// ------------------------------------------------------------------
__global__ void gather_kernel(const int* __restrict__ offb, const int* __restrict__ eidx,
                              const int* __restrict__ esrc, const float* __restrict__ att,
                              const float* __restrict__ C1, float* __restrict__ ws_seg)
{
    int p = blockIdx.x;
    int t = threadIdx.x;
    int s0 = offb[p], e0 = offb[p + 1];
    float acc = 0.f;
    int i = s0;
    for (; i + 1 < e0; i += 2) {
        int ed0 = eidx[i], ed1 = eidx[i + 1];
        float a0 = att[ed0], a1 = att[ed1];
        int sr0 = esrc[ed0], sr1 = esrc[ed1];
        acc += a0 * C1[(size_t)sr0 * 256 + 100 + t];
        acc += a1 * C1[(size_t)sr1 * 256 + 100 + t];
    }
    if (i < e0) {
        int ed = eidx[i];
        acc += att[ed] * C1[(size_t)esrc[ed] * 256 + 100 + t];
    }
    ws_seg[p * 128 + t] = acc;
}

// ------------------------------------------------------------------
// node update: rms-gate -> GRU -> LN -> MLP residual. 16 particles/block,
// thread (g,s) owns 8 contiguous cols c = s*8..s*8+7 of its particle.
// ------------------------------------------------------------------
__global__ __launch_bounds__(256) void node_update_kernel(
    const float* __restrict__ ws_seg, const float* __restrict__ ph,
    const float* __restrict__ W_ih, const float* __restrict__ b_ih,
    const float* __restrict__ W_hh, const float* __restrict__ b_hh,
    const float* __restrict__ ln_g, const float* __restrict__ ln_b,
    const float* __restrict__ W1, const float* __restrict__ b1,
    const float* __restrict__ W2, const float* __restrict__ b2,
    const float* __restrict__ rms_w, const float* __restrict__ lin_w,
    float* __restrict__ out, int P_)
{
    __shared__ float gl[16 * 132];
    __shared__ float hl[16 * 132];
    __shared__ float lnl[16 * 132];
    __shared__ float h1l[16 * 68];
    int tid = threadIdx.x;
    int g = tid >> 4, s = tid & 15;
    int p0 = blockIdx.x * 16;
    int p = p0 + g;

    for (int i = tid; i < 16 * 128; i += 256) {
        int row = i >> 7, c = i & 127;
        int pp = p0 + row;
        gl[row * 132 + c] = (pp < P_) ? ws_seg[pp * 128 + c] : 0.f;
        hl[row * 132 + c] = (pp < P_) ? ph[pp * 128 + c] : 0.f;
    }
    __syncthreads();

    int cb = s * 8;
    // rms + sigmoid gate
    float wsv[8];
    float ss = 0.f;
#pragma unroll
    for (int j = 0; j < 8; ++j) { wsv[j] = gl[g * 132 + cb + j]; ss += wsv[j] * wsv[j]; }
    ss += __shfl_xor(ss, 1); ss += __shfl_xor(ss, 2); ss += __shfl_xor(ss, 4); ss += __shfl_xor(ss, 8);
    float scale = rsqrtf(ss * (1.f / 128.f) + 1e-6f);
#pragma unroll
    for (int j = 0; j < 8; ++j) {
        int c = cb + j;
        float rv = wsv[j] * scale * rms_w[c];
        gl[g * 132 + c] = rv * sigmoidf_(wsv[j] * lin_w[c]);  // each thread overwrites only its own slots
    }
    __syncthreads();

    // GRU: 6 accumulators x 8 positions
    float air[8], aiz[8], ain[8], ahr[8], ahz[8], ahn[8];
#pragma unroll
    for (int j = 0; j < 8; ++j) {
        int c = cb + j;
        air[j] = b_ih[c]; aiz[j] = b_ih[128 + c]; ain[j] = b_ih[256 + c];
        ahr[j] = b_hh[c]; ahz[j] = b_hh[128 + c]; ahn[j] = b_hh[256 + c];
    }
    for (int k = 0; k < 128; ++k) {
        float gk = gl[g * 132 + k];
        float hk = hl[g * 132 + k];
        const float* wi = W_ih + k * 384 + cb;
        const float* wh = W_hh + k * 384 + cb;
        F8 wr = ld8(wi), wz = ld8(wi + 128), wn = ld8(wi + 256);
        F8 ur = ld8(wh), uz = ld8(wh + 128), un = ld8(wh + 256);
#pragma unroll
        for (int j = 0; j < 8; ++j) {
            air[j] += gk * wr.v[j]; aiz[j] += gk * wz.v[j]; ain[j] += gk * wn.v[j];
            ahr[j] += hk * ur.v[j]; ahz[j] += hk * uz.v[j]; ahn[j] += hk * un.v[j];
        }
    }
    float hn[8];
    float sm = 0.f, sq = 0.f;
#pragma unroll
    for (int j = 0; j < 8; ++j) {
        float r = sigmoidf_(air[j] + ahr[j]);
        float z = sigmoidf_(aiz[j] + ahz[j]);
        float n = tanhf(ain[j] + r * ahn[j]);
        float h = hl[g * 132 + cb + j];
        hn[j] = (1.f - z) * n + z * h;
        sm += hn[j]; sq += hn[j] * hn[j];
    }
    sm += __shfl_xor(sm, 1); sm += __shfl_xor(sm, 2); sm += __shfl_xor(sm, 4); sm += __shfl_xor(sm, 8);
    sq += __shfl_xor(sq, 1); sq += __shfl_xor(sq, 2); sq += __shfl_xor(sq, 4); sq += __shfl_xor(sq, 8);
    float mu = sm * (1.f / 128.f);
    float var = sq * (1.f / 128.f) - mu * mu;
    float iv = rsqrtf(var + 1e-5f);
#pragma unroll
    for (int j = 0; j < 8; ++j) {
        int c = cb + j;
        lnl[g * 132 + c] = (hn[j] - mu) * iv * ln_g[c] + ln_b[c];
    }
    __syncthreads();

    // MLP layer 1: each thread computes 4 of 64 hidden units
    int m0 = s * 4;
    float am[4] = {b1[m0], b1[m0 + 1], b1[m0 + 2], b1[m0 + 3]};
    for (int k = 0; k < 128; ++k) {
        float lk = lnl[g * 132 + k];
        float4 w = *(const float4*)(W1 + k * 64 + m0);
        am[0] += lk * w.x; am[1] += lk * w.y; am[2] += lk * w.z; am[3] += lk * w.w;
    }
    h1l[g * 68 + m0 + 0] = fmaxf(am[0], 0.f);
    h1l[g * 68 + m0 + 1] = fmaxf(am[1], 0.f);
    h1l[g * 68 + m0 + 2] = fmaxf(am[2], 0.f);
    h1l[g * 68 + m0 + 3] = fmaxf(am[3], 0.f);
    __syncthreads();

    // MLP layer 2 + residual (residual is ORIGINAL h, not h_new)
    float o[8];
#pragma unroll
    for (int j = 0; j < 8; ++j) { int c = cb + j; o[j] = hl[g * 132 + c] + b2[c]; }
    for (int m = 0; m < 64; ++m) {
        float hm = h1l[g * 68 + m];
        F8 w = ld8(W2 + m * 128 + cb);
#pragma unroll
        for (int j = 0; j < 8; ++j) o[j] += hm * w.v[j];
    }
    if (p < P_) {
        *(float4*)(out + (size_t)p * 128 + cb) = make_float4(o[0], o[1], o[2], o[3]);
        *(float4*)(out + (size_t)p * 128 + cb + 4) = make_float4(o[4], o[5], o[6], o[7]);
    }
}

// ------------------------------------------------------------------
extern "C" void kernel_launch(void* const* d_in, const int* in_sizes, int n_in,
                              void* d_out, int out_size, void* d_ws, size_t ws_size,
                              hipStream_t stream)
{
    const float* nh      = (const float*)d_in[0];
    const float* energy  = (const float*)d_in[1];
    const float* eta     = (const float*)d_in[2];
    const float* phi     = (const float*)d_in[3];
    const float* layer   = (const float*)d_in[4];
    const float* eta_l   = (const float*)d_in[5];
    const float* phi_l   = (const float*)d_in[6];
    const float* ene_l   = (const float*)d_in[7];
    const float* track   = (const float*)d_in[8];
    const float* ph      = (const float*)d_in[9];
    const float* grep    = (const float*)d_in[10];
    const int*   esrc    = (const int*)d_in[11];
    const int*   edst    = (const int*)d_in[12];
    const float* W_key   = (const float*)d_in[13];
    const float* b_key   = (const float*)d_in[14];
    const float* W_val   = (const float*)d_in[15];
    const float* b_val   = (const float*)d_in[16];
    const float* W_q     = (const float*)d_in[17];
    const float* b_q     = (const float*)d_in[18];
    const float* W_ih    = (const float*)d_in[19];
    const float* b_ih    = (const float*)d_in[20];
    const float* W_hh    = (const float*)d_in[21];
    const float* b_hh    = (const float*)d_in[22];
    const float* ln_g    = (const float*)d_in[23];
    const float* ln_b    = (const float*)d_in[24];
    const float* W1      = (const float*)d_in[25];
    const float* b1      = (const float*)d_in[26];
    const float* W2      = (const float*)d_in[27];
    const float* b2      = (const float*)d_in[28];
    const float* rms_w   = (const float*)d_in[29];
    const float* lin_w   = (const float*)d_in[30];

    const int N = in_sizes[1];
    const int P = in_sizes[9] / 128;
    const int E = in_sizes[11];

    // workspace layout (floats)
    float* w      = (float*)d_ws;
    float* skipb  = w;                          // N*32
    float* C1     = skipb + (size_t)N * 32;     // N*256 (keys 0..99, vals 100..227)
    float* Qb     = C1 + (size_t)N * 256;       // P*128
    float* Wp     = Qb + (size_t)P * 128;       // 288*256
    float* Wqp    = Wp + 288 * 256;             // 384*128
    float* bpn    = Wqp + 384 * 128;            // 256
    float* bpq    = bpn + 256;                  // 128
    float* attb   = bpq + 128;                  // E
    float* ws_seg = attb + E;                   // P*128
    int*   cnt    = (int*)(ws_seg + (size_t)P * 128);  // P
    int*   cur    = cnt + P;                    // P
    int*   offb   = cur + P;                    // P+1
    int*   eidx   = offb + (P + 1);             // E

    // 1. weight prep + skip features
    {
        int total = 288 * 256 + 384 * 128 + 256 + 128;
        prep_kernel<<<(total + THREADS - 1) / THREADS, THREADS, 0, stream>>>(
            W_key, W_val, W_q, b_key, b_val, b_q, Wp, Wqp, bpn, bpq);
        skip_kernel<<<(N + THREADS - 1) / THREADS, THREADS, 0, stream>>>(
            energy, eta, phi, layer, eta_l, phi_l, ene_l, track, skipb, N);
    }
    // 2. GEMMs
    gemm_kernel<0><<<dim3(2, (N + 127) / 128), THREADS, 0, stream>>>(
        nh, skipb, Wp, bpn, C1, N, 288, 256, 256);
    gemm_kernel<1><<<dim3(1, (P + 127) / 128), THREADS, 0, stream>>>(
        ph, grep, Wqp, bpq, Qb, P, 384, 128, 128);
    // 3. CSR build
    zero_ints<<<(2 * P + THREADS - 1) / THREADS, THREADS, 0, stream>>>(cnt, 2 * P);
    hist_kernel<<<(E + THREADS - 1) / THREADS, THREADS, 0, stream>>>(edst, cnt, E);
    scan_kernel<<<1, 1024, 0, stream>>>(cnt, offb, P);
    fill_kernel<<<(E + THREADS - 1) / THREADS, THREADS, 0, stream>>>(edst, offb, cur, eidx, E);
    // 4. attention + gather
    att_kernel<<<(E + 15) / 16, THREADS, 0, stream>>>(esrc, edst, C1, Qb, attb, E);
    gather_kernel<<<P, 128, 0, stream>>>(offb, eidx, esrc, attb, C1, ws_seg);
    // 5. node update
    node_update_kernel<<<(P + 15) / 16, THREADS, 0, stream>>>(
        ws_seg, ph, W_ih, b_ih, W_hh, b_hh, ln_g, ln_b,
        W1, b1, W2, b2, rms_w, lin_w, (float*)d_out, P);
}

// Round 3
// 433.615 us; speedup vs baseline: 1.5326x; 1.5326x over previous
//
#include <hip/hip_runtime.h>
#include <hip/hip_bf16.h>
#include <math.h>

#define THREADS 256

typedef __bf16 bf16_t;
typedef __bf16 bf16x8 __attribute__((ext_vector_type(8)));
typedef float f32x4 __attribute__((ext_vector_type(4)));

__device__ __forceinline__ float sigmoidf_(float x) { return 1.f / (1.f + expf(-x)); }

struct F8 { float v[8]; };
__device__ __forceinline__ F8 ld8(const float* p) {
    F8 r;
    float4 a = *(const float4*)p;
    float4 b = *(const float4*)(p + 4);
    r.v[0] = a.x; r.v[1] = a.y; r.v[2] = a.z; r.v[3] = a.w;
    r.v[4] = b.x; r.v[5] = b.y; r.v[6] = b.z; r.v[7] = b.w;
    return r;
}

__device__ __forceinline__ void gload_lds16(const void* g, void* l) {
    __builtin_amdgcn_global_load_lds((const __attribute__((address_space(1))) void*)g,
                                     (__attribute__((address_space(3))) void*)l, 16, 0, 0);
}

// ------------------------------------------------------------------
// prep: pack transposed bf16 weights.
// WbfT [256][288]: col c, k. c<100: W_key, 128<=c<256: W_val, else 0 (k>=283 -> 0)
// WqT  [128][384]: c<100: W_q else 0
// bpn[256] fp32: c<100 b_key, 128..255 b_val; bpq[128]: c<100 b_q
// ------------------------------------------------------------------
__global__ void prep_kernel(const float* __restrict__ W_key, const float* __restrict__ W_val,
                            const float* __restrict__ W_q, const float* __restrict__ b_key,
                            const float* __restrict__ b_val, const float* __restrict__ b_q,
                            bf16_t* __restrict__ WbfT, bf16_t* __restrict__ WqT,
                            float* __restrict__ bpn, float* __restrict__ bpq)
{
    int i = blockIdx.x * THREADS + threadIdx.x;
    const int NW = 256 * 288, NQ = 128 * 384;
    if (i < NW) {
        int c = i / 288, k = i - c * 288;
        float v = 0.f;
        if (k < 283) {
            if (c < 100) v = W_key[k * 100 + c];
            else if (c >= 128 && c < 256) v = W_val[k * 128 + (c - 128)];
        }
        WbfT[i] = (bf16_t)v;
    } else if (i < NW + NQ) {
        int j = i - NW;
        int c = j / 384, k = j - c * 384;
        WqT[j] = (bf16_t)((c < 100) ? W_q[k * 100 + c] : 0.f);
    } else if (i < NW + NQ + 256) {
        int c = i - NW - NQ;
        bpn[c] = (c < 100) ? b_key[c] : ((c >= 128 && c < 256) ? b_val[c - 128] : 0.f);
    } else if (i < NW + NQ + 256 + 128) {
        int c = i - NW - NQ - 256;
        bpq[c] = (c < 100) ? b_q[c] : 0.f;
    }
}

// ------------------------------------------------------------------
// convertA: node_hidden fp32 [N,256] -> Abf bf16 [Mpad,288] cols 0..255
// ------------------------------------------------------------------
__global__ void convertA_kernel(const float* __restrict__ nh, bf16_t* __restrict__ Abf, int N_)
{
    int id = blockIdx.x * THREADS + threadIdx.x;
    int row = id >> 5, cc = id & 31;
    bf16x8 v = {};
    if (row < N_) {
        const float* p = nh + (size_t)row * 256 + cc * 8;
        float4 a = *(const float4*)p;
        float4 b = *(const float4*)(p + 4);
        v[0] = (bf16_t)a.x; v[1] = (bf16_t)a.y; v[2] = (bf16_t)a.z; v[3] = (bf16_t)a.w;
        v[4] = (bf16_t)b.x; v[5] = (bf16_t)b.y; v[6] = (bf16_t)b.z; v[7] = (bf16_t)b.w;
    }
    *(bf16x8*)(Abf + (size_t)row * 288 + cc * 8) = v;
}

// skip features -> Abf cols 256..287 (27 real + 5 zero), one thread per row
__global__ void skip_kernel(const float* __restrict__ energy, const float* __restrict__ eta,
                            const float* __restrict__ phi, const float* __restrict__ layer,
                            const float* __restrict__ eta_l, const float* __restrict__ phi_l,
                            const float* __restrict__ ene_l, const float* __restrict__ track,
                            bf16_t* __restrict__ Abf, int N_, int Mpad)
{
    int n = blockIdx.x * THREADS + threadIdx.x;
    if (n >= Mpad) return;
    float o[32];
#pragma unroll
    for (int j = 0; j < 32; ++j) o[j] = 0.f;
    if (n < N_) {
        o[0] = (logf(energy[n]) - 4.0f) * 0.5f;
        o[1] = eta[n] * (1.f / 1.5f);
        o[2] = phi[n];
        o[3] = layer[n];
#pragma unroll
        for (int j = 0; j < 6; ++j) o[4 + j]  = eta_l[n * 6 + j] * (1.f / 1.5f);
#pragma unroll
        for (int j = 0; j < 6; ++j) o[10 + j] = phi_l[n * 6 + j];
#pragma unroll
        for (int j = 0; j < 6; ++j) o[16 + j] = ene_l[n * 6 + j];
#pragma unroll
        for (int j = 0; j < 5; ++j) o[22 + j] = track[n * 5 + j];
    }
    bf16_t* dst = Abf + (size_t)n * 288 + 256;
#pragma unroll
    for (int g = 0; g < 4; ++g) {
        bf16x8 v;
#pragma unroll
        for (int j = 0; j < 8; ++j) v[j] = (bf16_t)o[g * 8 + j];
        *(bf16x8*)(dst + g * 8) = v;
    }
}

// convertQ: concat(particle_hidden[P,128], global_rep[P,256]) -> Aq bf16 [Mq,384]
__global__ void convertQ_kernel(const float* __restrict__ ph, const float* __restrict__ grep,
                                bf16_t* __restrict__ Aq, int P_)
{
    int id = blockIdx.x * THREADS + threadIdx.x;
    int row = id / 48, cc = id - row * 48;
    bf16x8 v = {};
    if (row < P_) {
        const float* p = (cc < 16) ? (ph + (size_t)row * 128 + cc * 8)
                                   : (grep + (size_t)row * 256 + (cc - 16) * 8);
        float4 a = *(const float4*)p;
        float4 b = *(const float4*)(p + 4);
        v[0] = (bf16_t)a.x; v[1] = (bf16_t)a.y; v[2] = (bf16_t)a.z; v[3] = (bf16_t)a.w;
        v[4] = (bf16_t)b.x; v[5] = (bf16_t)b.y; v[6] = (bf16_t)b.z; v[7] = (bf16_t)b.w;
    }
    *(bf16x8*)(Aq + (size_t)row * 384 + cc * 8) = v;
}

// ------------------------------------------------------------------
// bf16 MFMA GEMM, m97 structure: 128x128 tile, BK=32, 4 waves, 64x64/wave.
// A [Mpad][K] bf16 row-major, BT [Ncols][K] bf16 (transposed weights).
// MODE 0: split-write Kb (col<128) / Vb (col-128), bf16, node GEMM.
// MODE 1: write Qb bf16 [*,128].
// ------------------------------------------------------------------
template <int MODE>
__global__ __launch_bounds__(256) void mfma_gemm(
    const bf16_t* __restrict__ A, const bf16_t* __restrict__ BT,
    const float* __restrict__ bias,
    bf16_t* __restrict__ out0, bf16_t* __restrict__ out1, int K)
{
    __shared__ short AsS[128 * 32];  // [row][k] 64B rows
    __shared__ short BsS[128 * 32];  // [col][k]
    int tid = threadIdx.x;
    int lane = tid & 63, w = tid >> 6;
    int la = lane & 15, hi = lane >> 4;
    int m0 = (w & 1) * 64, n0 = (w >> 1) * 64;
    int row0 = blockIdx.y * 128, col0 = blockIdx.x * 128;

    f32x4 zero4 = {0.f, 0.f, 0.f, 0.f};
    f32x4 acc[4][4];
#pragma unroll
    for (int i = 0; i < 4; ++i)
#pragma unroll
        for (int j = 0; j < 4; ++j) acc[i][j] = zero4;

    for (int kt = 0; kt < K; kt += 32) {
        // stage: 512 chunks of 16B each for A and B
#pragma unroll
        for (int it = 0; it < 2; ++it) {
            int c = tid + it * 256;
            int r = c >> 2, kc = c & 3;
            gload_lds16(A + (size_t)(row0 + r) * K + kt + kc * 8, AsS + c * 8);
            gload_lds16(BT + (size_t)(col0 + r) * K + kt + kc * 8, BsS + c * 8);
        }
        __syncthreads();
        bf16x8 a[4], b[4];
#pragma unroll
        for (int i = 0; i < 4; ++i)
            a[i] = *(const bf16x8*)(AsS + (m0 + i * 16 + la) * 32 + hi * 8);
#pragma unroll
        for (int j = 0; j < 4; ++j)
            b[j] = *(const bf16x8*)(BsS + (n0 + j * 16 + la) * 32 + hi * 8);
#pragma unroll
        for (int i = 0; i < 4; ++i)
#pragma unroll
            for (int j = 0; j < 4; ++j)
                acc[i][j] = __builtin_amdgcn_mfma_f32_16x16x32_bf16(a[i], b[j], acc[i][j], 0, 0, 0);
        __syncthreads();
    }

#pragma unroll
    for (int i = 0; i < 4; ++i) {
#pragma unroll
        for (int j = 0; j < 4; ++j) {
            int col = col0 + n0 + j * 16 + la;
            float bb = bias[col];
#pragma unroll
            for (int r = 0; r < 4; ++r) {
                int row = row0 + m0 + i * 16 + hi * 4 + r;
                float v = acc[i][j][r] + bb;
                if (MODE == 0) {
                    if (col < 128) out0[(size_t)row * 128 + col] = (bf16_t)v;
                    else           out1[(size_t)row * 128 + (col - 128)] = (bf16_t)v;
                } else {
                    out0[(size_t)row * 128 + col] = (bf16_t)v;
                }
            }
        }
    }
}

// ------------------------------------------------------------------
// per-edge attention: 16 lanes/edge, dot over 128 bf16 (cols >=100 are 0)
// ------------------------------------------------------------------
__global__ void att_kernel(const int* __restrict__ esrc, const int* __restrict__ edst,
                           const bf16_t* __restrict__ Kb, const bf16_t* __restrict__ Qb,
                           float* __restrict__ att, int E_)
{
    int tid = threadIdx.x;
    int e = blockIdx.x * 16 + (tid >> 4);
    int s = tid & 15;
    float sum = 0.f;
    if (e < E_) {
        const bf16_t* kp = Kb + (size_t)esrc[e] * 128 + s * 8;
        const bf16_t* qp = Qb + (size_t)edst[e] * 128 + s * 8;
        bf16x8 k8 = *(const bf16x8*)kp;
        bf16x8 q8 = *(const bf16x8*)qp;
#pragma unroll
        for (int j = 0; j < 8; ++j) sum += (float)k8[j] * (float)q8[j];
    }
    sum += __shfl_xor(sum, 1);
    sum += __shfl_xor(sum, 2);
    sum += __shfl_xor(sum, 4);
    sum += __shfl_xor(sum, 8);
    if (e < E_ && s == 0) att[e] = fmaxf(sum * 0.1f, 0.f);
}

// ------------------------------------------------------------------
// CSR build
// ------------------------------------------------------------------
__global__ void zero_ints(int* __restrict__ p, int n)
{
    int i = blockIdx.x * THREADS + threadIdx.x;
    if (i < n) p[i] = 0;
}

__global__ void hist_kernel(const int* __restrict__ dst, int* __restrict__ cnt, int E_)
{
    int i = blockIdx.x * THREADS + threadIdx.x;
    if (i < E_) atomicAdd(&cnt[dst[i]], 1);
}

// single-block shfl-based exclusive scan; 1024 threads x 10 elems covers P+1<=10240
__global__ void scan_kernel(const int* __restrict__ cnt, int* __restrict__ offb, int P_)
{
    __shared__ int wsum[16];
    int tid = threadIdx.x;
    int lane = tid & 63, w = tid >> 6;
    int base = tid * 10;
    int c[10];
    int s = 0;
#pragma unroll
    for (int j = 0; j < 10; ++j) {
        int i = base + j;
        c[j] = (i < P_) ? cnt[i] : 0;
        s += c[j];
    }
    int pre = s;  // inclusive scan over wave
    for (int o = 1; o < 64; o <<= 1) {
        int t = __shfl_up(pre, o);
        if (lane >= o) pre += t;
    }
    if (lane == 63) wsum[w] = pre;
    __syncthreads();
    if (w == 0 && lane < 16) {
        int v = wsum[lane];
        for (int o = 1; o < 16; o <<= 1) {
            int t = __shfl_up(v, o, 16);
            if (lane >= o) v += t;
        }
        wsum[lane] = v;  // inclusive wave sums
    }
    __syncthreads();
    int waveoff = (w == 0) ? 0 : wsum[w - 1];
    int run = waveoff + pre - s;  // exclusive start for this thread
#pragma unroll
    for (int j = 0; j < 10; ++j) {
        int i = base + j;
        if (i <= P_) offb[i] = run;
        run += c[j];
    }
}

__global__ void fill_kernel(const int* __restrict__ dst, const int* __restrict__ offb,
                            int* __restrict__ cur, int* __restrict__ eidx, int E_)
{
    int i = blockIdx.x * THREADS + threadIdx.x;
    if (i < E_) {
        int d = dst[i];
        int pos = atomicAdd(&cur[d], 1);
        eidx[offb[d] + pos] = i;
    }
}

// ------------------------------------------------------------------
// gather: one block (128 threads) per particle, vals bf16
// ------------------------------------------------------------------
__global__ void gather_kernel(const int* __restrict__ offb, const int* __restrict__ eidx,
                              const int* __restrict__ esrc, const float* __restrict__ att,
                              const bf16_t* __restrict__ Vb, float* __restrict__ ws_seg)
{
    int p = blockIdx.x;
    int t = threadIdx.x;
    int s0 = offb[p], e0 = offb[p + 1];
    float acc = 0.f;
    int i = s0;
    for (; i + 1 < e0; i += 2) {
        int ed0 = eidx[i], ed1 = eidx[i + 1];
        float a0 = att[ed0], a1 = att[ed1];
        int sr0 = esrc[ed0], sr1 = esrc[ed1];
        acc += a0 * (float)Vb[(size_t)sr0 * 128 + t];
        acc += a1 * (float)Vb[(size_t)sr1 * 128 + t];
    }
    if (i < e0) {
        int ed = eidx[i];
        acc += att[ed] * (float)Vb[(size_t)esrc[ed] * 128 + t];
    }
    ws_seg[p * 128 + t] = acc;
}

// ------------------------------------------------------------------
// node update: rms-gate -> GRU -> LN -> MLP residual
// ------------------------------------------------------------------
__global__ __launch_bounds__(256) void node_update_kernel(
    const float* __restrict__ ws_seg, const float* __restrict__ ph,
    const float* __restrict__ W_ih, const float* __restrict__ b_ih,
    const float* __restrict__ W_hh, const float* __restrict__ b_hh,
    const float* __restrict__ ln_g, const float* __restrict__ ln_b,
    const float* __restrict__ W1, const float* __restrict__ b1,
    const float* __restrict__ W2, const float* __restrict__ b2,
    const float* __restrict__ rms_w, const float* __restrict__ lin_w,
    float* __restrict__ out, int P_)
{
    __shared__ float gl[16 * 132];
    __shared__ float hl[16 * 132];
    __shared__ float lnl[16 * 132];
    __shared__ float h1l[16 * 68];
    int tid = threadIdx.x;
    int g = tid >> 4, s = tid & 15;
    int p0 = blockIdx.x * 16;
    int p = p0 + g;

    for (int i = tid; i < 16 * 128; i += 256) {
        int row = i >> 7, c = i & 127;
        int pp = p0 + row;
        gl[row * 132 + c] = (pp < P_) ? ws_seg[pp * 128 + c] : 0.f;
        hl[row * 132 + c] = (pp < P_) ? ph[pp * 128 + c] : 0.f;
    }
    __syncthreads();

    int cb = s * 8;
    float wsv[8];
    float ss = 0.f;
#pragma unroll
    for (int j = 0; j < 8; ++j) { wsv[j] = gl[g * 132 + cb + j]; ss += wsv[j] * wsv[j]; }
    ss += __shfl_xor(ss, 1); ss += __shfl_xor(ss, 2); ss += __shfl_xor(ss, 4); ss += __shfl_xor(ss, 8);
    float scale = rsqrtf(ss * (1.f / 128.f) + 1e-6f);
#pragma unroll
    for (int j = 0; j < 8; ++j) {
        int c = cb + j;
        float rv = wsv[j] * scale * rms_w[c];
        gl[g * 132 + c] = rv * sigmoidf_(wsv[j] * lin_w[c]);
    }
    __syncthreads();

    float air[8], aiz[8], ain[8], ahr[8], ahz[8], ahn[8];
#pragma unroll
    for (int j = 0; j < 8; ++j) {
        int c = cb + j;
        air[j] = b_ih[c]; aiz[j] = b_ih[128 + c]; ain[j] = b_ih[256 + c];
        ahr[j] = b_hh[c]; ahz[j] = b_hh[128 + c]; ahn[j] = b_hh[256 + c];
    }
    for (int k = 0; k < 128; ++k) {
        float gk = gl[g * 132 + k];
        float hk = hl[g * 132 + k];
        const float* wi = W_ih + k * 384 + cb;
        const float* wh = W_hh + k * 384 + cb;
        F8 wr = ld8(wi), wz = ld8(wi + 128), wn = ld8(wi + 256);
        F8 ur = ld8(wh), uz = ld8(wh + 128), un = ld8(wh + 256);
#pragma unroll
        for (int j = 0; j < 8; ++j) {
            air[j] += gk * wr.v[j]; aiz[j] += gk * wz.v[j]; ain[j] += gk * wn.v[j];
            ahr[j] += hk * ur.v[j]; ahz[j] += hk * uz.v[j]; ahn[j] += hk * un.v[j];
        }
    }
    float hn[8];
    float sm = 0.f, sq = 0.f;
#pragma unroll
    for (int j = 0; j < 8; ++j) {
        float r = sigmoidf_(air[j] + ahr[j]);
        float z = sigmoidf_(aiz[j] + ahz[j]);
        float n = tanhf(ain[j] + r * ahn[j]);
        float h = hl[g * 132 + cb + j];
        hn[j] = (1.f - z) * n + z * h;
        sm += hn[j]; sq += hn[j] * hn[j];
    }
    sm += __shfl_xor(sm, 1); sm += __shfl_xor(sm, 2); sm += __shfl_xor(sm, 4); sm += __shfl_xor(sm, 8);
    sq += __shfl_xor(sq, 1); sq += __shfl_xor(sq, 2); sq += __shfl_xor(sq, 4); sq += __shfl_xor(sq, 8);
    float mu = sm * (1.f / 128.f);
    float var = sq * (1.f / 128.f) - mu * mu;
    float iv = rsqrtf(var + 1e-5f);
#pragma unroll
    for (int j = 0; j < 8; ++j) {
        int c = cb + j;
        lnl[g * 132 + c] = (hn[j] - mu) * iv * ln_g[c] + ln_b[c];
    }
    __syncthreads();

    int m0 = s * 4;
    float am[4] = {b1[m0], b1[m0 + 1], b1[m0 + 2], b1[m0 + 3]};
    for (int k = 0; k < 128; ++k) {
        float lk = lnl[g * 132 + k];
        float4 w = *(const float4*)(W1 + k * 64 + m0);
        am[0] += lk * w.x; am[1] += lk * w.y; am[2] += lk * w.z; am[3] += lk * w.w;
    }
    h1l[g * 68 + m0 + 0] = fmaxf(am[0], 0.f);
    h1l[g * 68 + m0 + 1] = fmaxf(am[1], 0.f);
    h1l[g * 68 + m0 + 2] = fmaxf(am[2], 0.f);
    h1l[g * 68 + m0 + 3] = fmaxf(am[3], 0.f);
    __syncthreads();

    float o[8];
#pragma unroll
    for (int j = 0; j < 8; ++j) { int c = cb + j; o[j] = hl[g * 132 + c] + b2[c]; }
    for (int m = 0; m < 64; ++m) {
        float hm = h1l[g * 68 + m];
        F8 w = ld8(W2 + m * 128 + cb);
#pragma unroll
        for (int j = 0; j < 8; ++j) o[j] += hm * w.v[j];
    }
    if (p < P_) {
        *(float4*)(out + (size_t)p * 128 + cb) = make_float4(o[0], o[1], o[2], o[3]);
        *(float4*)(out + (size_t)p * 128 + cb + 4) = make_float4(o[4], o[5], o[6], o[7]);
    }
}

// ------------------------------------------------------------------
extern "C" void kernel_launch(void* const* d_in, const int* in_sizes, int n_in,
                              void* d_out, int out_size, void* d_ws, size_t ws_size,
                              hipStream_t stream)
{
    const float* nh      = (const float*)d_in[0];
    const float* energy  = (const float*)d_in[1];
    const float* eta     = (const float*)d_in[2];
    const float* phi     = (const float*)d_in[3];
    const float* layer   = (const float*)d_in[4];
    const float* eta_l   = (const float*)d_in[5];
    const float* phi_l   = (const float*)d_in[6];
    const float* ene_l   = (const float*)d_in[7];
    const float* track   = (const float*)d_in[8];
    const float* ph      = (const float*)d_in[9];
    const float* grep    = (const float*)d_in[10];
    const int*   esrc    = (const int*)d_in[11];
    const int*   edst    = (const int*)d_in[12];
    const float* W_key   = (const float*)d_in[13];
    const float* b_key   = (const float*)d_in[14];
    const float* W_val   = (const float*)d_in[15];
    const float* b_val   = (const float*)d_in[16];
    const float* W_q     = (const float*)d_in[17];
    const float* b_q     = (const float*)d_in[18];
    const float* W_ih    = (const float*)d_in[19];
    const float* b_ih    = (const float*)d_in[20];
    const float* W_hh    = (const float*)d_in[21];
    const float* b_hh    = (const float*)d_in[22];
    const float* ln_g    = (const float*)d_in[23];
    const float* ln_b    = (const float*)d_in[24];
    const float* W1      = (const float*)d_in[25];
    const float* b1      = (const float*)d_in[26];
    const float* W2      = (const float*)d_in[27];
    const float* b2      = (const float*)d_in[28];
    const float* rms_w   = (const float*)d_in[29];
    const float* lin_w   = (const float*)d_in[30];

    const int N = in_sizes[1];
    const int P = in_sizes[9] / 128;
    const int E = in_sizes[11];
    const int Mpad = ((N + 127) / 128) * 128;   // 100096
    const int Mq   = ((P + 127) / 128) * 128;   // 10112

    // workspace layout (byte offsets, 256B aligned)
    char* base = (char*)d_ws;
    size_t off = 0;
    auto alloc = [&](size_t bytes) { void* p = base + off; off = (off + bytes + 255) & ~(size_t)255; return p; };
    bf16_t* Abf   = (bf16_t*)alloc((size_t)Mpad * 288 * 2);
    bf16_t* Aq    = (bf16_t*)alloc((size_t)Mq * 384 * 2);
    bf16_t* WbfT  = (bf16_t*)alloc(256 * 288 * 2);
    bf16_t* WqT   = (bf16_t*)alloc(128 * 384 * 2);
    float*  bpn   = (float*)alloc(256 * 4);
    float*  bpq   = (float*)alloc(128 * 4);
    bf16_t* Kb    = (bf16_t*)alloc((size_t)Mpad * 128 * 2);
    bf16_t* Vb    = (bf16_t*)alloc((size_t)Mpad * 128 * 2);
    bf16_t* Qb    = (bf16_t*)alloc((size_t)Mq * 128 * 2);
    float*  attb  = (float*)alloc((size_t)E * 4);
    float*  ws_seg= (float*)alloc((size_t)P * 128 * 4);
    // cnt and cur MUST be contiguous: zero_ints(cnt, 2*P) covers both.
    // (round-2 crash: separate 256B-aligned allocs left cur's tail poisoned)
    int*    cnt   = (int*)alloc((size_t)(2 * P) * 4);
    int*    cur   = cnt + P;
    int*    offb  = (int*)alloc((size_t)(P + 1) * 4);
    int*    eidx  = (int*)alloc((size_t)E * 4);

    // 1. weight prep + input conversion
    {
        int total = 256 * 288 + 128 * 384 + 256 + 128;
        prep_kernel<<<(total + THREADS - 1) / THREADS, THREADS, 0, stream>>>(
            W_key, W_val, W_q, b_key, b_val, b_q, WbfT, WqT, bpn, bpq);
        convertA_kernel<<<Mpad * 32 / THREADS, THREADS, 0, stream>>>(nh, Abf, N);
        skip_kernel<<<(Mpad + THREADS - 1) / THREADS, THREADS, 0, stream>>>(
            energy, eta, phi, layer, eta_l, phi_l, ene_l, track, Abf, N, Mpad);
        convertQ_kernel<<<Mq * 48 / THREADS, THREADS, 0, stream>>>(ph, grep, Aq, P);
    }
    // 2. MFMA GEMMs
    mfma_gemm<0><<<dim3(2, Mpad / 128), THREADS, 0, stream>>>(Abf, WbfT, bpn, Kb, Vb, 288);
    mfma_gemm<1><<<dim3(1, Mq / 128), THREADS, 0, stream>>>(Aq, WqT, bpq, Qb, nullptr, 384);
    // 3. CSR build
    zero_ints<<<(2 * P + THREADS - 1) / THREADS, THREADS, 0, stream>>>(cnt, 2 * P);
    hist_kernel<<<(E + THREADS - 1) / THREADS, THREADS, 0, stream>>>(edst, cnt, E);
    scan_kernel<<<1, 1024, 0, stream>>>(cnt, offb, P);
    fill_kernel<<<(E + THREADS - 1) / THREADS, THREADS, 0, stream>>>(edst, offb, cur, eidx, E);
    // 4. attention + gather
    att_kernel<<<(E + 15) / 16, THREADS, 0, stream>>>(esrc, edst, Kb, Qb, attb, E);
    gather_kernel<<<P, 128, 0, stream>>>(offb, eidx, esrc, attb, Vb, ws_seg);
    // 5. node update
    node_update_kernel<<<(P + 15) / 16, THREADS, 0, stream>>>(
        ws_seg, ph, W_ih, b_ih, W_hh, b_hh, ln_g, ln_b,
        W1, b1, W2, b2, rms_w, lin_w, (float*)d_out, P);
}

// Round 4
// 329.774 us; speedup vs baseline: 2.0152x; 1.3149x over previous
//
#include <hip/hip_runtime.h>
#include <hip/hip_bf16.h>
#include <math.h>

#define THREADS 256

typedef __bf16 bf16_t;
typedef __bf16 bf16x8 __attribute__((ext_vector_type(8)));
typedef float f32x4 __attribute__((ext_vector_type(4)));

__device__ __forceinline__ float sigmoidf_(float x) { return 1.f / (1.f + expf(-x)); }

__device__ __forceinline__ void gload_lds16(const void* g, void* l) {
    __builtin_amdgcn_global_load_lds((const __attribute__((address_space(1))) void*)g,
                                     (__attribute__((address_space(3))) void*)l, 16, 0, 0);
}

// ------------------------------------------------------------------
// prep: pack transposed bf16 weights for key/val/q GEMMs.
// WbfT [256][288], WqT [128][384], bpn[256], bpq[128]
// ------------------------------------------------------------------
__global__ void prep_kernel(const float* __restrict__ W_key, const float* __restrict__ W_val,
                            const float* __restrict__ W_q, const float* __restrict__ b_key,
                            const float* __restrict__ b_val, const float* __restrict__ b_q,
                            bf16_t* __restrict__ WbfT, bf16_t* __restrict__ WqT,
                            float* __restrict__ bpn, float* __restrict__ bpq)
{
    int i = blockIdx.x * THREADS + threadIdx.x;
    const int NW = 256 * 288, NQ = 128 * 384;
    if (i < NW) {
        int c = i / 288, k = i - c * 288;
        float v = 0.f;
        if (k < 283) {
            if (c < 100) v = W_key[k * 100 + c];
            else if (c >= 128 && c < 256) v = W_val[k * 128 + (c - 128)];
        }
        WbfT[i] = (bf16_t)v;
    } else if (i < NW + NQ) {
        int j = i - NW;
        int c = j / 384, k = j - c * 384;
        WqT[j] = (bf16_t)((c < 100) ? W_q[k * 100 + c] : 0.f);
    } else if (i < NW + NQ + 256) {
        int c = i - NW - NQ;
        bpn[c] = (c < 100) ? b_key[c] : ((c >= 128 && c < 256) ? b_val[c - 128] : 0.f);
    } else if (i < NW + NQ + 256 + 128) {
        int c = i - NW - NQ - 256;
        bpq[c] = (c < 100) ? b_q[c] : 0.f;
    }
}

// ------------------------------------------------------------------
// prep2: pack GRU block-diag BTg [768][256]: col c<384 <- W_ih (k<128),
// c>=384 <- W_hh (k>=128). W1Tp [128][128] (cols 64.. zero),
// W2Tp [128][128] (k>=64 zero). bgru[768]=[b_ih|b_hh], b1p[128].
// ------------------------------------------------------------------
__global__ void prep2_kernel(const float* __restrict__ W_ih, const float* __restrict__ W_hh,
                             const float* __restrict__ b_ih, const float* __restrict__ b_hh,
                             const float* __restrict__ W1, const float* __restrict__ b1,
                             const float* __restrict__ W2,
                             bf16_t* __restrict__ BTg, bf16_t* __restrict__ W1Tp,
                             bf16_t* __restrict__ W2Tp, float* __restrict__ bgru,
                             float* __restrict__ b1p)
{
    int i = blockIdx.x * THREADS + threadIdx.x;
    const int NG = 768 * 256, N1 = 128 * 128, N2 = 128 * 128;
    if (i < NG) {
        int c = i >> 8, k = i & 255;
        float v = 0.f;
        if (c < 384) { if (k < 128) v = W_ih[k * 384 + c]; }
        else         { if (k >= 128) v = W_hh[(k - 128) * 384 + (c - 384)]; }
        BTg[i] = (bf16_t)v;
    } else if (i < NG + N1) {
        int j = i - NG; int c = j >> 7, k = j & 127;
        W1Tp[j] = (bf16_t)((c < 64) ? W1[k * 64 + c] : 0.f);
    } else if (i < NG + N1 + N2) {
        int j = i - NG - N1; int c = j >> 7, k = j & 127;
        W2Tp[j] = (bf16_t)((k < 64) ? W2[k * 128 + c] : 0.f);
    } else if (i < NG + N1 + N2 + 768) {
        int c = i - NG - N1 - N2;
        bgru[c] = (c < 384) ? b_ih[c] : b_hh[c - 384];
    } else if (i < NG + N1 + N2 + 768 + 128) {
        int c = i - NG - N1 - N2 - 768;
        b1p[c] = (c < 64) ? b1[c] : 0.f;
    }
}

// ------------------------------------------------------------------
// convertA: node_hidden fp32 [N,256] -> Abf bf16 [Mpad,288] cols 0..255
// ------------------------------------------------------------------
__global__ void convertA_kernel(const float* __restrict__ nh, bf16_t* __restrict__ Abf, int N_)
{
    int id = blockIdx.x * THREADS + threadIdx.x;
    int row = id >> 5, cc = id & 31;
    bf16x8 v = {};
    if (row < N_) {
        const float* p = nh + (size_t)row * 256 + cc * 8;
        float4 a = *(const float4*)p;
        float4 b = *(const float4*)(p + 4);
        v[0] = (bf16_t)a.x; v[1] = (bf16_t)a.y; v[2] = (bf16_t)a.z; v[3] = (bf16_t)a.w;
        v[4] = (bf16_t)b.x; v[5] = (bf16_t)b.y; v[6] = (bf16_t)b.z; v[7] = (bf16_t)b.w;
    }
    *(bf16x8*)(Abf + (size_t)row * 288 + cc * 8) = v;
}

// skip features -> Abf cols 256..287 (27 real + 5 zero)
__global__ void skip_kernel(const float* __restrict__ energy, const float* __restrict__ eta,
                            const float* __restrict__ phi, const float* __restrict__ layer,
                            const float* __restrict__ eta_l, const float* __restrict__ phi_l,
                            const float* __restrict__ ene_l, const float* __restrict__ track,
                            bf16_t* __restrict__ Abf, int N_, int Mpad)
{
    int n = blockIdx.x * THREADS + threadIdx.x;
    if (n >= Mpad) return;
    float o[32];
#pragma unroll
    for (int j = 0; j < 32; ++j) o[j] = 0.f;
    if (n < N_) {
        o[0] = (logf(energy[n]) - 4.0f) * 0.5f;
        o[1] = eta[n] * (1.f / 1.5f);
        o[2] = phi[n];
        o[3] = layer[n];
#pragma unroll
        for (int j = 0; j < 6; ++j) o[4 + j]  = eta_l[n * 6 + j] * (1.f / 1.5f);
#pragma unroll
        for (int j = 0; j < 6; ++j) o[10 + j] = phi_l[n * 6 + j];
#pragma unroll
        for (int j = 0; j < 6; ++j) o[16 + j] = ene_l[n * 6 + j];
#pragma unroll
        for (int j = 0; j < 5; ++j) o[22 + j] = track[n * 5 + j];
    }
    bf16_t* dst = Abf + (size_t)n * 288 + 256;
#pragma unroll
    for (int g = 0; g < 4; ++g) {
        bf16x8 v;
#pragma unroll
        for (int j = 0; j < 8; ++j) v[j] = (bf16_t)o[g * 8 + j];
        *(bf16x8*)(dst + g * 8) = v;
    }
}

// convertQ: concat(particle_hidden[P,128], global_rep[P,256]) -> Aq bf16 [Mq,384]
__global__ void convertQ_kernel(const float* __restrict__ ph, const float* __restrict__ grep,
                                bf16_t* __restrict__ Aq, int P_)
{
    int id = blockIdx.x * THREADS + threadIdx.x;
    int row = id / 48, cc = id - row * 48;
    bf16x8 v = {};
    if (row < P_) {
        const float* p = (cc < 16) ? (ph + (size_t)row * 128 + cc * 8)
                                   : (grep + (size_t)row * 256 + (cc - 16) * 8);
        float4 a = *(const float4*)p;
        float4 b = *(const float4*)(p + 4);
        v[0] = (bf16_t)a.x; v[1] = (bf16_t)a.y; v[2] = (bf16_t)a.z; v[3] = (bf16_t)a.w;
        v[4] = (bf16_t)b.x; v[5] = (bf16_t)b.y; v[6] = (bf16_t)b.z; v[7] = (bf16_t)b.w;
    }
    *(bf16x8*)(Aq + (size_t)row * 384 + cc * 8) = v;
}

// ------------------------------------------------------------------
// bf16 MFMA GEMM, m97 structure: 128x128 tile, BK=32, 4 waves, 64x64/wave.
// A [.][K] bf16 row-major (rows padded to tile), BT [Ncols][K] bf16.
// MODE 0: split-write Kb/Vb bf16           MODE 1: Qb bf16
// MODE 2: fp32 out, ldc=768 (GRU gi|gh)    MODE 3: bf16 out + relu (MLP1)
// MODE 4: fp32 out = acc+bias+resid, guarded row<Mlimit (MLP2+residual)
// ------------------------------------------------------------------
template <int MODE>
__global__ __launch_bounds__(256) void mfma_gemm(
    const bf16_t* __restrict__ A, const bf16_t* __restrict__ BT,
    const float* __restrict__ bias, void* __restrict__ out0v, void* __restrict__ out1v,
    const float* __restrict__ resid, int K, int Mlimit)
{
    __shared__ short AsS[128 * 32];  // [row][k] 64B rows
    __shared__ short BsS[128 * 32];  // [col][k]
    int tid = threadIdx.x;
    int lane = tid & 63, w = tid >> 6;
    int la = lane & 15, hi = lane >> 4;
    int m0 = (w & 1) * 64, n0 = (w >> 1) * 64;
    int row0 = blockIdx.y * 128, col0 = blockIdx.x * 128;

    f32x4 zero4 = {0.f, 0.f, 0.f, 0.f};
    f32x4 acc[4][4];
#pragma unroll
    for (int i = 0; i < 4; ++i)
#pragma unroll
        for (int j = 0; j < 4; ++j) acc[i][j] = zero4;

    for (int kt = 0; kt < K; kt += 32) {
#pragma unroll
        for (int it = 0; it < 2; ++it) {
            int c = tid + it * 256;
            int r = c >> 2, kc = c & 3;
            gload_lds16(A + (size_t)(row0 + r) * K + kt + kc * 8, AsS + c * 8);
            gload_lds16(BT + (size_t)(col0 + r) * K + kt + kc * 8, BsS + c * 8);
        }
        __syncthreads();
        bf16x8 a[4], b[4];
#pragma unroll
        for (int i = 0; i < 4; ++i)
            a[i] = *(const bf16x8*)(AsS + (m0 + i * 16 + la) * 32 + hi * 8);
#pragma unroll
        for (int j = 0; j < 4; ++j)
            b[j] = *(const bf16x8*)(BsS + (n0 + j * 16 + la) * 32 + hi * 8);
#pragma unroll
        for (int i = 0; i < 4; ++i)
#pragma unroll
            for (int j = 0; j < 4; ++j)
                acc[i][j] = __builtin_amdgcn_mfma_f32_16x16x32_bf16(a[i], b[j], acc[i][j], 0, 0, 0);
        __syncthreads();
    }

#pragma unroll
    for (int i = 0; i < 4; ++i) {
#pragma unroll
        for (int j = 0; j < 4; ++j) {
            int col = col0 + n0 + j * 16 + la;
            float bb = bias[col];
#pragma unroll
            for (int r = 0; r < 4; ++r) {
                int row = row0 + m0 + i * 16 + hi * 4 + r;
                float v = acc[i][j][r] + bb;
                if (MODE == 0) {
                    bf16_t* o0 = (bf16_t*)out0v; bf16_t* o1 = (bf16_t*)out1v;
                    if (col < 128) o0[(size_t)row * 128 + col] = (bf16_t)v;
                    else           o1[(size_t)row * 128 + (col - 128)] = (bf16_t)v;
                } else if (MODE == 1) {
                    ((bf16_t*)out0v)[(size_t)row * 128 + col] = (bf16_t)v;
                } else if (MODE == 2) {
                    ((float*)out0v)[(size_t)row * 768 + col] = v;
                } else if (MODE == 3) {
                    ((bf16_t*)out0v)[(size_t)row * 128 + col] = (bf16_t)fmaxf(v, 0.f);
                } else {  // MODE 4
                    if (row < Mlimit)
                        ((float*)out0v)[(size_t)row * 128 + col] = v + resid[(size_t)row * 128 + col];
                }
            }
        }
    }
}

// ------------------------------------------------------------------
// per-edge attention: 16 lanes/edge, dot over 128 bf16
// ------------------------------------------------------------------
__global__ void att_kernel(const int* __restrict__ esrc, const int* __restrict__ edst,
                           const bf16_t* __restrict__ Kb, const bf16_t* __restrict__ Qb,
                           float* __restrict__ att, int E_)
{
    int tid = threadIdx.x;
    int e = blockIdx.x * 16 + (tid >> 4);
    int s = tid & 15;
    float sum = 0.f;
    if (e < E_) {
        const bf16_t* kp = Kb + (size_t)esrc[e] * 128 + s * 8;
        const bf16_t* qp = Qb + (size_t)edst[e] * 128 + s * 8;
        bf16x8 k8 = *(const bf16x8*)kp;
        bf16x8 q8 = *(const bf16x8*)qp;
#pragma unroll
        for (int j = 0; j < 8; ++j) sum += (float)k8[j] * (float)q8[j];
    }
    sum += __shfl_xor(sum, 1);
    sum += __shfl_xor(sum, 2);
    sum += __shfl_xor(sum, 4);
    sum += __shfl_xor(sum, 8);
    if (e < E_ && s == 0) att[e] = fmaxf(sum * 0.1f, 0.f);
}

// ------------------------------------------------------------------
// CSR build
// ------------------------------------------------------------------
__global__ void zero_ints(int* __restrict__ p, int n)
{
    int i = blockIdx.x * THREADS + threadIdx.x;
    if (i < n) p[i] = 0;
}

__global__ void hist_kernel(const int* __restrict__ dst, int* __restrict__ cnt, int E_)
{
    int i = blockIdx.x * THREADS + threadIdx.x;
    if (i < E_) atomicAdd(&cnt[dst[i]], 1);
}

// single-block shfl-based exclusive scan; 1024 threads x 10 elems covers P+1<=10240
__global__ void scan_kernel(const int* __restrict__ cnt, int* __restrict__ offb, int P_)
{
    __shared__ int wsum[16];
    int tid = threadIdx.x;
    int lane = tid & 63, w = tid >> 6;
    int base = tid * 10;
    int c[10];
    int s = 0;
#pragma unroll
    for (int j = 0; j < 10; ++j) {
        int i = base + j;
        c[j] = (i < P_) ? cnt[i] : 0;
        s += c[j];
    }
    int pre = s;
    for (int o = 1; o < 64; o <<= 1) {
        int t = __shfl_up(pre, o);
        if (lane >= o) pre += t;
    }
    if (lane == 63) wsum[w] = pre;
    __syncthreads();
    if (w == 0 && lane < 16) {
        int v = wsum[lane];
        for (int o = 1; o < 16; o <<= 1) {
            int t = __shfl_up(v, o, 16);
            if (lane >= o) v += t;
        }
        wsum[lane] = v;
    }
    __syncthreads();
    int waveoff = (w == 0) ? 0 : wsum[w - 1];
    int run = waveoff + pre - s;
#pragma unroll
    for (int j = 0; j < 10; ++j) {
        int i = base + j;
        if (i <= P_) offb[i] = run;
        run += c[j];
    }
}

__global__ void fill_kernel(const int* __restrict__ dst, const int* __restrict__ offb,
                            int* __restrict__ cur, int* __restrict__ eidx, int E_)
{
    int i = blockIdx.x * THREADS + threadIdx.x;
    if (i < E_) {
        int d = dst[i];
        int pos = atomicAdd(&cur[d], 1);
        eidx[offb[d] + pos] = i;
    }
}

// ------------------------------------------------------------------
// gather: one block (128 threads) per particle, vals bf16
// ------------------------------------------------------------------
__global__ void gather_kernel(const int* __restrict__ offb, const int* __restrict__ eidx,
                              const int* __restrict__ esrc, const float* __restrict__ att,
                              const bf16_t* __restrict__ Vb, float* __restrict__ ws_seg)
{
    int p = blockIdx.x;
    int t = threadIdx.x;
    int s0 = offb[p], e0 = offb[p + 1];
    float acc = 0.f;
    int i = s0;
    for (; i + 1 < e0; i += 2) {
        int ed0 = eidx[i], ed1 = eidx[i + 1];
        float a0 = att[ed0], a1 = att[ed1];
        int sr0 = esrc[ed0], sr1 = esrc[ed1];
        acc += a0 * (float)Vb[(size_t)sr0 * 128 + t];
        acc += a1 * (float)Vb[(size_t)sr1 * 128 + t];
    }
    if (i < e0) {
        int ed = eidx[i];
        acc += att[ed] * (float)Vb[(size_t)esrc[ed] * 128 + t];
    }
    ws_seg[p * 128 + t] = acc;
}

// ------------------------------------------------------------------
// gate: rms-norm * sigmoid gate -> AG = [gated | h] bf16 [Mq,256]
// 16 lanes/particle, 8 cols each. Pad rows (p>=P) zeroed.
// ------------------------------------------------------------------
__global__ void gate_kernel(const float* __restrict__ ws_seg, const float* __restrict__ ph,
                            const float* __restrict__ rms_w, const float* __restrict__ lin_w,
                            bf16_t* __restrict__ AG, int P_, int Mq)
{
    int tid = threadIdx.x;
    int g = tid >> 4, s = tid & 15;
    int p = blockIdx.x * 16 + g;
    if (p >= Mq) return;
    int cb = s * 8;
    if (p >= P_) {
        bf16x8 z = {};
        *(bf16x8*)(AG + (size_t)p * 256 + cb) = z;
        *(bf16x8*)(AG + (size_t)p * 256 + 128 + cb) = z;
        return;
    }
    const float* wp = ws_seg + (size_t)p * 128 + cb;
    float4 a = *(const float4*)wp, b = *(const float4*)(wp + 4);
    float wsv[8] = {a.x, a.y, a.z, a.w, b.x, b.y, b.z, b.w};
    float ss = 0.f;
#pragma unroll
    for (int j = 0; j < 8; ++j) ss += wsv[j] * wsv[j];
    ss += __shfl_xor(ss, 1); ss += __shfl_xor(ss, 2); ss += __shfl_xor(ss, 4); ss += __shfl_xor(ss, 8);
    float scale = rsqrtf(ss * (1.f / 128.f) + 1e-6f);
    const float* hp = ph + (size_t)p * 128 + cb;
    float4 ha = *(const float4*)hp, hb = *(const float4*)(hp + 4);
    float hv[8] = {ha.x, ha.y, ha.z, ha.w, hb.x, hb.y, hb.z, hb.w};
    bf16x8 gv, hvb;
#pragma unroll
    for (int j = 0; j < 8; ++j) {
        int c = cb + j;
        float rv = wsv[j] * scale * rms_w[c];
        gv[j] = (bf16_t)(rv * sigmoidf_(wsv[j] * lin_w[c]));
        hvb[j] = (bf16_t)hv[j];
    }
    *(bf16x8*)(AG + (size_t)p * 256 + cb) = gv;
    *(bf16x8*)(AG + (size_t)p * 256 + 128 + cb) = hvb;
}

// ------------------------------------------------------------------
// gru+ln pointwise: read G768 [Mq,768] fp32 (gi|gh, biases included),
// h=ph fp32; compute h_new, LayerNorm -> LNb bf16 [Mq,128]
// ------------------------------------------------------------------
__global__ void gru_ln_kernel(const float* __restrict__ G768, const float* __restrict__ ph,
                              const float* __restrict__ ln_g, const float* __restrict__ ln_b,
                              bf16_t* __restrict__ LNb, int P_, int Mq)
{
    int tid = threadIdx.x;
    int g = tid >> 4, s = tid & 15;
    int p = blockIdx.x * 16 + g;
    if (p >= Mq) return;
    int cb = s * 8;
    if (p >= P_) {
        bf16x8 z = {};
        *(bf16x8*)(LNb + (size_t)p * 128 + cb) = z;
        return;
    }
    const float* G = G768 + (size_t)p * 768;
    float ir[8], iz[8], in_[8], hr[8], hz[8], hn_[8], hv[8];
#pragma unroll
    for (int q = 0; q < 2; ++q) {
        float4 v;
        v = *(const float4*)(G + cb + q * 4);        ir[q*4]=v.x; ir[q*4+1]=v.y; ir[q*4+2]=v.z; ir[q*4+3]=v.w;
        v = *(const float4*)(G + 128 + cb + q * 4);  iz[q*4]=v.x; iz[q*4+1]=v.y; iz[q*4+2]=v.z; iz[q*4+3]=v.w;
        v = *(const float4*)(G + 256 + cb + q * 4);  in_[q*4]=v.x; in_[q*4+1]=v.y; in_[q*4+2]=v.z; in_[q*4+3]=v.w;
        v = *(const float4*)(G + 384 + cb + q * 4);  hr[q*4]=v.x; hr[q*4+1]=v.y; hr[q*4+2]=v.z; hr[q*4+3]=v.w;
        v = *(const float4*)(G + 512 + cb + q * 4);  hz[q*4]=v.x; hz[q*4+1]=v.y; hz[q*4+2]=v.z; hz[q*4+3]=v.w;
        v = *(const float4*)(G + 640 + cb + q * 4);  hn_[q*4]=v.x; hn_[q*4+1]=v.y; hn_[q*4+2]=v.z; hn_[q*4+3]=v.w;
        v = *(const float4*)(ph + (size_t)p * 128 + cb + q * 4);
        hv[q*4]=v.x; hv[q*4+1]=v.y; hv[q*4+2]=v.z; hv[q*4+3]=v.w;
    }
    float hn[8];
    float sm = 0.f, sq = 0.f;
#pragma unroll
    for (int j = 0; j < 8; ++j) {
        float r = sigmoidf_(ir[j] + hr[j]);
        float z = sigmoidf_(iz[j] + hz[j]);
        float n = tanhf(in_[j] + r * hn_[j]);
        hn[j] = (1.f - z) * n + z * hv[j];
        sm += hn[j]; sq += hn[j] * hn[j];
    }
    sm += __shfl_xor(sm, 1); sm += __shfl_xor(sm, 2); sm += __shfl_xor(sm, 4); sm += __shfl_xor(sm, 8);
    sq += __shfl_xor(sq, 1); sq += __shfl_xor(sq, 2); sq += __shfl_xor(sq, 4); sq += __shfl_xor(sq, 8);
    float mu = sm * (1.f / 128.f);
    float var = sq * (1.f / 128.f) - mu * mu;
    float iv = rsqrtf(var + 1e-5f);
    bf16x8 o;
#pragma unroll
    for (int j = 0; j < 8; ++j) {
        int c = cb + j;
        o[j] = (bf16_t)((hn[j] - mu) * iv * ln_g[c] + ln_b[c]);
    }
    *(bf16x8*)(LNb + (size_t)p * 128 + cb) = o;
}

// ------------------------------------------------------------------
extern "C" void kernel_launch(void* const* d_in, const int* in_sizes, int n_in,
                              void* d_out, int out_size, void* d_ws, size_t ws_size,
                              hipStream_t stream)
{
    const float* nh      = (const float*)d_in[0];
    const float* energy  = (const float*)d_in[1];
    const float* eta     = (const float*)d_in[2];
    const float* phi     = (const float*)d_in[3];
    const float* layer   = (const float*)d_in[4];
    const float* eta_l   = (const float*)d_in[5];
    const float* phi_l   = (const float*)d_in[6];
    const float* ene_l   = (const float*)d_in[7];
    const float* track   = (const float*)d_in[8];
    const float* ph      = (const float*)d_in[9];
    const float* grep    = (const float*)d_in[10];
    const int*   esrc    = (const int*)d_in[11];
    const int*   edst    = (const int*)d_in[12];
    const float* W_key   = (const float*)d_in[13];
    const float* b_key   = (const float*)d_in[14];
    const float* W_val   = (const float*)d_in[15];
    const float* b_val   = (const float*)d_in[16];
    const float* W_q     = (const float*)d_in[17];
    const float* b_q     = (const float*)d_in[18];
    const float* W_ih    = (const float*)d_in[19];
    const float* b_ih    = (const float*)d_in[20];
    const float* W_hh    = (const float*)d_in[21];
    const float* b_hh    = (const float*)d_in[22];
    const float* ln_g    = (const float*)d_in[23];
    const float* ln_b    = (const float*)d_in[24];
    const float* W1      = (const float*)d_in[25];
    const float* b1      = (const float*)d_in[26];
    const float* W2      = (const float*)d_in[27];
    const float* b2      = (const float*)d_in[28];
    const float* rms_w   = (const float*)d_in[29];
    const float* lin_w   = (const float*)d_in[30];

    const int N = in_sizes[1];
    const int P = in_sizes[9] / 128;
    const int E = in_sizes[11];
    const int Mpad = ((N + 127) / 128) * 128;   // 100096
    const int Mq   = ((P + 127) / 128) * 128;   // 10112

    // workspace layout (byte offsets, 256B aligned)
    char* base = (char*)d_ws;
    size_t off = 0;
    auto alloc = [&](size_t bytes) { void* p = base + off; off = (off + bytes + 255) & ~(size_t)255; return p; };
    bf16_t* Abf   = (bf16_t*)alloc((size_t)Mpad * 288 * 2);   // 57.6 MB
    bf16_t* Aq    = (bf16_t*)alloc((size_t)Mq * 384 * 2);     // 7.8 MB
    bf16_t* WbfT  = (bf16_t*)alloc(256 * 288 * 2);
    bf16_t* WqT   = (bf16_t*)alloc(128 * 384 * 2);
    float*  bpn   = (float*)alloc(256 * 4);
    float*  bpq   = (float*)alloc(128 * 4);
    bf16_t* Kb    = (bf16_t*)alloc((size_t)Mpad * 128 * 2);
    bf16_t* Vb    = (bf16_t*)alloc((size_t)Mpad * 128 * 2);
    bf16_t* Qb    = (bf16_t*)alloc((size_t)Mq * 128 * 2);
    float*  attb  = (float*)alloc((size_t)E * 4);
    float*  ws_seg= (float*)alloc((size_t)P * 128 * 4);
    // cnt and cur MUST be contiguous: zero_ints(cnt, 2*P) covers both.
    int*    cnt   = (int*)alloc((size_t)(2 * P) * 4);
    int*    cur   = cnt + P;
    int*    offb  = (int*)alloc((size_t)(P + 1) * 4);
    int*    eidx  = (int*)alloc((size_t)E * 4);
    // node-update buffers
    bf16_t* AG    = (bf16_t*)alloc((size_t)Mq * 256 * 2);     // [gated|h]
    bf16_t* BTg   = (bf16_t*)alloc(768 * 256 * 2);
    bf16_t* W1Tp  = (bf16_t*)alloc(128 * 128 * 2);
    bf16_t* W2Tp  = (bf16_t*)alloc(128 * 128 * 2);
    float*  bgru  = (float*)alloc(768 * 4);
    float*  b1p   = (float*)alloc(128 * 4);
    // Aliased (stream-ordered reuse of dead regions):
    //   G768 [Mq,768] fp32 (31 MB) lives in Abf (57.6 MB, dead after mfma_gemm<0>)
    //   LNb, M1 [Mq,128] bf16 live in Aq (7.8 MB, dead after mfma_gemm<1>)
    float*  G768  = (float*)Abf;
    bf16_t* LNb   = Aq;
    bf16_t* M1    = Aq + (size_t)Mq * 128;

    // 1. weight prep + input conversion
    {
        int total = 256 * 288 + 128 * 384 + 256 + 128;
        prep_kernel<<<(total + THREADS - 1) / THREADS, THREADS, 0, stream>>>(
            W_key, W_val, W_q, b_key, b_val, b_q, WbfT, WqT, bpn, bpq);
        int total2 = 768 * 256 + 128 * 128 + 128 * 128 + 768 + 128;
        prep2_kernel<<<(total2 + THREADS - 1) / THREADS, THREADS, 0, stream>>>(
            W_ih, W_hh, b_ih, b_hh, W1, b1, W2, BTg, W1Tp, W2Tp, bgru, b1p);
        convertA_kernel<<<Mpad * 32 / THREADS, THREADS, 0, stream>>>(nh, Abf, N);
        skip_kernel<<<(Mpad + THREADS - 1) / THREADS, THREADS, 0, stream>>>(
            energy, eta, phi, layer, eta_l, phi_l, ene_l, track, Abf, N, Mpad);
        convertQ_kernel<<<Mq * 48 / THREADS, THREADS, 0, stream>>>(ph, grep, Aq, P);
    }
    // 2. MFMA GEMMs (keys/vals and q)
    mfma_gemm<0><<<dim3(2, Mpad / 128), THREADS, 0, stream>>>(
        Abf, WbfT, bpn, Kb, Vb, nullptr, 288, 0);
    mfma_gemm<1><<<dim3(1, Mq / 128), THREADS, 0, stream>>>(
        Aq, WqT, bpq, Qb, nullptr, nullptr, 384, 0);
    // 3. CSR build
    zero_ints<<<(2 * P + THREADS - 1) / THREADS, THREADS, 0, stream>>>(cnt, 2 * P);
    hist_kernel<<<(E + THREADS - 1) / THREADS, THREADS, 0, stream>>>(edst, cnt, E);
    scan_kernel<<<1, 1024, 0, stream>>>(cnt, offb, P);
    fill_kernel<<<(E + THREADS - 1) / THREADS, THREADS, 0, stream>>>(edst, offb, cur, eidx, E);
    // 4. attention + gather
    att_kernel<<<(E + 15) / 16, THREADS, 0, stream>>>(esrc, edst, Kb, Qb, attb, E);
    gather_kernel<<<P, 128, 0, stream>>>(offb, eidx, esrc, attb, Vb, ws_seg);
    // 5. node update: gate -> GRU GEMM -> pointwise+LN -> MLP1 -> MLP2+residual
    gate_kernel<<<Mq / 16, THREADS, 0, stream>>>(ws_seg, ph, rms_w, lin_w, AG, P, Mq);
    mfma_gemm<2><<<dim3(6, Mq / 128), THREADS, 0, stream>>>(
        AG, BTg, bgru, G768, nullptr, nullptr, 256, 0);
    gru_ln_kernel<<<Mq / 16, THREADS, 0, stream>>>(G768, ph, ln_g, ln_b, LNb, P, Mq);
    mfma_gemm<3><<<dim3(1, Mq / 128), THREADS, 0, stream>>>(
        LNb, W1Tp, b1p, M1, nullptr, nullptr, 128, 0);
    mfma_gemm<4><<<dim3(1, Mq / 128), THREADS, 0, stream>>>(
        M1, W2Tp, b2, d_out, nullptr, ph, 128, P);
}

// Round 5
// 264.927 us; speedup vs baseline: 2.5084x; 1.2448x over previous
//
#include <hip/hip_runtime.h>
#include <hip/hip_bf16.h>
#include <math.h>

#define THREADS 256

typedef __bf16 bf16_t;
typedef __bf16 bf16x8 __attribute__((ext_vector_type(8)));
typedef float f32x4 __attribute__((ext_vector_type(4)));

__device__ __forceinline__ float sigmoidf_(float x) { return 1.f / (1.f + expf(-x)); }

__device__ __forceinline__ void gload_lds16(const void* g, void* l) {
    __builtin_amdgcn_global_load_lds((const __attribute__((address_space(1))) void*)g,
                                     (__attribute__((address_space(3))) void*)l, 16, 0, 0);
}

// ------------------------------------------------------------------
// prep: pack transposed bf16 weights for key/val/q GEMMs.
// WbfT [256][288], WqT [128][384], bpn[256], bpq[128]
// ------------------------------------------------------------------
__global__ void prep_kernel(const float* __restrict__ W_key, const float* __restrict__ W_val,
                            const float* __restrict__ W_q, const float* __restrict__ b_key,
                            const float* __restrict__ b_val, const float* __restrict__ b_q,
                            bf16_t* __restrict__ WbfT, bf16_t* __restrict__ WqT,
                            float* __restrict__ bpn, float* __restrict__ bpq)
{
    int i = blockIdx.x * THREADS + threadIdx.x;
    const int NW = 256 * 288, NQ = 128 * 384;
    if (i < NW) {
        int c = i / 288, k = i - c * 288;
        float v = 0.f;
        if (k < 283) {
            if (c < 100) v = W_key[k * 100 + c];
            else if (c >= 128 && c < 256) v = W_val[k * 128 + (c - 128)];
        }
        WbfT[i] = (bf16_t)v;
    } else if (i < NW + NQ) {
        int j = i - NW;
        int c = j / 384, k = j - c * 384;
        WqT[j] = (bf16_t)((c < 100) ? W_q[k * 100 + c] : 0.f);
    } else if (i < NW + NQ + 256) {
        int c = i - NW - NQ;
        bpn[c] = (c < 100) ? b_key[c] : ((c >= 128 && c < 256) ? b_val[c - 128] : 0.f);
    } else if (i < NW + NQ + 256 + 128) {
        int c = i - NW - NQ - 256;
        bpq[c] = (c < 100) ? b_q[c] : 0.f;
    }
}

// ------------------------------------------------------------------
// prep2: pack GRU block-diag BTg [768][256], W1Tp [128][128],
// W2Tp [128][128], bgru[768], b1p[128]
// ------------------------------------------------------------------
__global__ void prep2_kernel(const float* __restrict__ W_ih, const float* __restrict__ W_hh,
                             const float* __restrict__ b_ih, const float* __restrict__ b_hh,
                             const float* __restrict__ W1, const float* __restrict__ b1,
                             const float* __restrict__ W2,
                             bf16_t* __restrict__ BTg, bf16_t* __restrict__ W1Tp,
                             bf16_t* __restrict__ W2Tp, float* __restrict__ bgru,
                             float* __restrict__ b1p)
{
    int i = blockIdx.x * THREADS + threadIdx.x;
    const int NG = 768 * 256, N1 = 128 * 128, N2 = 128 * 128;
    if (i < NG) {
        int c = i >> 8, k = i & 255;
        float v = 0.f;
        if (c < 384) { if (k < 128) v = W_ih[k * 384 + c]; }
        else         { if (k >= 128) v = W_hh[(k - 128) * 384 + (c - 384)]; }
        BTg[i] = (bf16_t)v;
    } else if (i < NG + N1) {
        int j = i - NG; int c = j >> 7, k = j & 127;
        W1Tp[j] = (bf16_t)((c < 64) ? W1[k * 64 + c] : 0.f);
    } else if (i < NG + N1 + N2) {
        int j = i - NG - N1; int c = j >> 7, k = j & 127;
        W2Tp[j] = (bf16_t)((k < 64) ? W2[k * 128 + c] : 0.f);
    } else if (i < NG + N1 + N2 + 768) {
        int c = i - NG - N1 - N2;
        bgru[c] = (c < 384) ? b_ih[c] : b_hh[c - 384];
    } else if (i < NG + N1 + N2 + 768 + 128) {
        int c = i - NG - N1 - N2 - 768;
        b1p[c] = (c < 64) ? b1[c] : 0.f;
    }
}

// ------------------------------------------------------------------
// convertA: node_hidden fp32 [N,256] -> Abf bf16 [Mpad,288] cols 0..255
// ------------------------------------------------------------------
__global__ void convertA_kernel(const float* __restrict__ nh, bf16_t* __restrict__ Abf, int N_)
{
    int id = blockIdx.x * THREADS + threadIdx.x;
    int row = id >> 5, cc = id & 31;
    bf16x8 v = {};
    if (row < N_) {
        const float* p = nh + (size_t)row * 256 + cc * 8;
        float4 a = *(const float4*)p;
        float4 b = *(const float4*)(p + 4);
        v[0] = (bf16_t)a.x; v[1] = (bf16_t)a.y; v[2] = (bf16_t)a.z; v[3] = (bf16_t)a.w;
        v[4] = (bf16_t)b.x; v[5] = (bf16_t)b.y; v[6] = (bf16_t)b.z; v[7] = (bf16_t)b.w;
    }
    *(bf16x8*)(Abf + (size_t)row * 288 + cc * 8) = v;
}

// skip features -> Abf cols 256..287 (27 real + 5 zero)
__global__ void skip_kernel(const float* __restrict__ energy, const float* __restrict__ eta,
                            const float* __restrict__ phi, const float* __restrict__ layer,
                            const float* __restrict__ eta_l, const float* __restrict__ phi_l,
                            const float* __restrict__ ene_l, const float* __restrict__ track,
                            bf16_t* __restrict__ Abf, int N_, int Mpad)
{
    int n = blockIdx.x * THREADS + threadIdx.x;
    if (n >= Mpad) return;
    float o[32];
#pragma unroll
    for (int j = 0; j < 32; ++j) o[j] = 0.f;
    if (n < N_) {
        o[0] = (logf(energy[n]) - 4.0f) * 0.5f;
        o[1] = eta[n] * (1.f / 1.5f);
        o[2] = phi[n];
        o[3] = layer[n];
#pragma unroll
        for (int j = 0; j < 6; ++j) o[4 + j]  = eta_l[n * 6 + j] * (1.f / 1.5f);
#pragma unroll
        for (int j = 0; j < 6; ++j) o[10 + j] = phi_l[n * 6 + j];
#pragma unroll
        for (int j = 0; j < 6; ++j) o[16 + j] = ene_l[n * 6 + j];
#pragma unroll
        for (int j = 0; j < 5; ++j) o[22 + j] = track[n * 5 + j];
    }
    bf16_t* dst = Abf + (size_t)n * 288 + 256;
#pragma unroll
    for (int g = 0; g < 4; ++g) {
        bf16x8 v;
#pragma unroll
        for (int j = 0; j < 8; ++j) v[j] = (bf16_t)o[g * 8 + j];
        *(bf16x8*)(dst + g * 8) = v;
    }
}

// convertQ: concat(particle_hidden[P,128], global_rep[P,256]) -> Aq bf16 [Mq,384]
__global__ void convertQ_kernel(const float* __restrict__ ph, const float* __restrict__ grep,
                                bf16_t* __restrict__ Aq, int P_)
{
    int id = blockIdx.x * THREADS + threadIdx.x;
    int row = id / 48, cc = id - row * 48;
    bf16x8 v = {};
    if (row < P_) {
        const float* p = (cc < 16) ? (ph + (size_t)row * 128 + cc * 8)
                                   : (grep + (size_t)row * 256 + (cc - 16) * 8);
        float4 a = *(const float4*)p;
        float4 b = *(const float4*)(p + 4);
        v[0] = (bf16_t)a.x; v[1] = (bf16_t)a.y; v[2] = (bf16_t)a.z; v[3] = (bf16_t)a.w;
        v[4] = (bf16_t)b.x; v[5] = (bf16_t)b.y; v[6] = (bf16_t)b.z; v[7] = (bf16_t)b.w;
    }
    *(bf16x8*)(Aq + (size_t)row * 384 + cc * 8) = v;
}

// ------------------------------------------------------------------
// bf16 MFMA GEMM, m97 structure: 128x128 tile, BK=32, 4 waves, 64x64/wave.
// MODE 0: split-write Kb/Vb bf16           MODE 1: Qb bf16
// MODE 2: fp32 out, ldc=768 (GRU gi|gh)    MODE 3: bf16 out + relu (MLP1)
// MODE 4: fp32 out = acc+bias+resid, guarded row<Mlimit (MLP2+residual)
// ------------------------------------------------------------------
template <int MODE>
__global__ __launch_bounds__(256) void mfma_gemm(
    const bf16_t* __restrict__ A, const bf16_t* __restrict__ BT,
    const float* __restrict__ bias, void* __restrict__ out0v, void* __restrict__ out1v,
    const float* __restrict__ resid, int K, int Mlimit)
{
    __shared__ short AsS[128 * 32];  // [row][k] 64B rows
    __shared__ short BsS[128 * 32];  // [col][k]
    int tid = threadIdx.x;
    int lane = tid & 63, w = tid >> 6;
    int la = lane & 15, hi = lane >> 4;
    int m0 = (w & 1) * 64, n0 = (w >> 1) * 64;
    int row0 = blockIdx.y * 128, col0 = blockIdx.x * 128;

    f32x4 zero4 = {0.f, 0.f, 0.f, 0.f};
    f32x4 acc[4][4];
#pragma unroll
    for (int i = 0; i < 4; ++i)
#pragma unroll
        for (int j = 0; j < 4; ++j) acc[i][j] = zero4;

    for (int kt = 0; kt < K; kt += 32) {
#pragma unroll
        for (int it = 0; it < 2; ++it) {
            int c = tid + it * 256;
            int r = c >> 2, kc = c & 3;
            gload_lds16(A + (size_t)(row0 + r) * K + kt + kc * 8, AsS + c * 8);
            gload_lds16(BT + (size_t)(col0 + r) * K + kt + kc * 8, BsS + c * 8);
        }
        __syncthreads();
        bf16x8 a[4], b[4];
#pragma unroll
        for (int i = 0; i < 4; ++i)
            a[i] = *(const bf16x8*)(AsS + (m0 + i * 16 + la) * 32 + hi * 8);
#pragma unroll
        for (int j = 0; j < 4; ++j)
            b[j] = *(const bf16x8*)(BsS + (n0 + j * 16 + la) * 32 + hi * 8);
#pragma unroll
        for (int i = 0; i < 4; ++i)
#pragma unroll
            for (int j = 0; j < 4; ++j)
                acc[i][j] = __builtin_amdgcn_mfma_f32_16x16x32_bf16(a[i], b[j], acc[i][j], 0, 0, 0);
        __syncthreads();
    }

#pragma unroll
    for (int i = 0; i < 4; ++i) {
#pragma unroll
        for (int j = 0; j < 4; ++j) {
            int col = col0 + n0 + j * 16 + la;
            float bb = bias[col];
#pragma unroll
            for (int r = 0; r < 4; ++r) {
                int row = row0 + m0 + i * 16 + hi * 4 + r;
                float v = acc[i][j][r] + bb;
                if (MODE == 0) {
                    bf16_t* o0 = (bf16_t*)out0v; bf16_t* o1 = (bf16_t*)out1v;
                    if (col < 128) o0[(size_t)row * 128 + col] = (bf16_t)v;
                    else           o1[(size_t)row * 128 + (col - 128)] = (bf16_t)v;
                } else if (MODE == 1) {
                    ((bf16_t*)out0v)[(size_t)row * 128 + col] = (bf16_t)v;
                } else if (MODE == 2) {
                    ((float*)out0v)[(size_t)row * 768 + col] = v;
                } else if (MODE == 3) {
                    ((bf16_t*)out0v)[(size_t)row * 128 + col] = (bf16_t)fmaxf(v, 0.f);
                } else {  // MODE 4
                    if (row < Mlimit)
                        ((float*)out0v)[(size_t)row * 128 + col] = v + resid[(size_t)row * 128 + col];
                }
            }
        }
    }
}

// ------------------------------------------------------------------
// CSR build
// ------------------------------------------------------------------
__global__ void zero_ints(int* __restrict__ p, int n)
{
    int i = blockIdx.x * THREADS + threadIdx.x;
    if (i < n) p[i] = 0;
}

__global__ void hist_kernel(const int* __restrict__ dst, int* __restrict__ cnt, int E_)
{
    int i = blockIdx.x * THREADS + threadIdx.x;
    if (i < E_) atomicAdd(&cnt[dst[i]], 1);
}

// single-block shfl-based exclusive scan; 1024 threads x 10 elems covers P+1<=10240
__global__ void scan_kernel(const int* __restrict__ cnt, int* __restrict__ offb, int P_)
{
    __shared__ int wsum[16];
    int tid = threadIdx.x;
    int lane = tid & 63, w = tid >> 6;
    int base = tid * 10;
    int c[10];
    int s = 0;
#pragma unroll
    for (int j = 0; j < 10; ++j) {
        int i = base + j;
        c[j] = (i < P_) ? cnt[i] : 0;
        s += c[j];
    }
    int pre = s;
    for (int o = 1; o < 64; o <<= 1) {
        int t = __shfl_up(pre, o);
        if (lane >= o) pre += t;
    }
    if (lane == 63) wsum[w] = pre;
    __syncthreads();
    if (w == 0 && lane < 16) {
        int v = wsum[lane];
        for (int o = 1; o < 16; o <<= 1) {
            int t = __shfl_up(v, o, 16);
            if (lane >= o) v += t;
        }
        wsum[lane] = v;
    }
    __syncthreads();
    int waveoff = (w == 0) ? 0 : wsum[w - 1];
    int run = waveoff + pre - s;
#pragma unroll
    for (int j = 0; j < 10; ++j) {
        int i = base + j;
        if (i <= P_) offb[i] = run;
        run += c[j];
    }
}

// fill: store SRC NODE ID directly (not edge id) -> one less indirection
__global__ void fill_src_kernel(const int* __restrict__ dst, const int* __restrict__ src,
                                const int* __restrict__ offb, int* __restrict__ cur,
                                int* __restrict__ csrc, int E_)
{
    int i = blockIdx.x * THREADS + threadIdx.x;
    if (i < E_) {
        int d = dst[i];
        int pos = atomicAdd(&cur[d], 1);
        csrc[offb[d] + pos] = src[i];
    }
}

// ------------------------------------------------------------------
// fused attention+gather: 1 wave per particle, 4 particles/block.
// lane = (g=lane>>4 edge-group, c=lane&15 col-chunk of 8).
// per edge: 16-lane group reads K[src],V[src] 16B slices; dot(q,k) via
// shfl_xor reduce; acc += relu(0.1*dot)*v. 2-edge unroll -> 16 rows in
// flight per wave. Cross-group reduce via shfl_xor(16/32).
// ------------------------------------------------------------------
__global__ __launch_bounds__(256) void edge_kernel(
    const int* __restrict__ offb, const int* __restrict__ csrc,
    const bf16_t* __restrict__ Kb, const bf16_t* __restrict__ Vb,
    const bf16_t* __restrict__ Qb, float* __restrict__ ws_seg, int P_)
{
    int tid = threadIdx.x;
    int p = blockIdx.x * 4 + (tid >> 6);
    if (p >= P_) return;
    int lane = tid & 63;
    int c = lane & 15, g = lane >> 4;

    bf16x8 q8 = *(const bf16x8*)(Qb + (size_t)p * 128 + c * 8);
    float qf[8];
#pragma unroll
    for (int j = 0; j < 8; ++j) qf[j] = (float)q8[j];

    int s0 = offb[p], e0 = offb[p + 1];
    float acc[8] = {};

    int i = s0 + g;
    for (; i + 4 < e0; i += 8) {
        int sA = csrc[i], sB = csrc[i + 4];
        const bf16_t* kpA = Kb + (size_t)sA * 128 + c * 8;
        const bf16_t* vpA = Vb + (size_t)sA * 128 + c * 8;
        const bf16_t* kpB = Kb + (size_t)sB * 128 + c * 8;
        const bf16_t* vpB = Vb + (size_t)sB * 128 + c * 8;
        bf16x8 kA = *(const bf16x8*)kpA;
        bf16x8 vA = *(const bf16x8*)vpA;
        bf16x8 kB = *(const bf16x8*)kpB;
        bf16x8 vB = *(const bf16x8*)vpB;
        float dA = 0.f, dB = 0.f;
#pragma unroll
        for (int j = 0; j < 8; ++j) { dA += qf[j] * (float)kA[j]; dB += qf[j] * (float)kB[j]; }
        dA += __shfl_xor(dA, 1); dB += __shfl_xor(dB, 1);
        dA += __shfl_xor(dA, 2); dB += __shfl_xor(dB, 2);
        dA += __shfl_xor(dA, 4); dB += __shfl_xor(dB, 4);
        dA += __shfl_xor(dA, 8); dB += __shfl_xor(dB, 8);
        float aA = fmaxf(dA * 0.1f, 0.f);
        float aB = fmaxf(dB * 0.1f, 0.f);
#pragma unroll
        for (int j = 0; j < 8; ++j)
            acc[j] += aA * (float)vA[j] + aB * (float)vB[j];
    }
    if (i < e0) {
        int sA = csrc[i];
        bf16x8 kA = *(const bf16x8*)(Kb + (size_t)sA * 128 + c * 8);
        bf16x8 vA = *(const bf16x8*)(Vb + (size_t)sA * 128 + c * 8);
        float dA = 0.f;
#pragma unroll
        for (int j = 0; j < 8; ++j) dA += qf[j] * (float)kA[j];
        dA += __shfl_xor(dA, 1);
        dA += __shfl_xor(dA, 2);
        dA += __shfl_xor(dA, 4);
        dA += __shfl_xor(dA, 8);
        float aA = fmaxf(dA * 0.1f, 0.f);
#pragma unroll
        for (int j = 0; j < 8; ++j) acc[j] += aA * (float)vA[j];
    }

    // reduce across the 4 edge-groups (lane bits 4,5)
#pragma unroll
    for (int j = 0; j < 8; ++j) {
        acc[j] += __shfl_xor(acc[j], 16);
        acc[j] += __shfl_xor(acc[j], 32);
    }
    if (g == 0) {
        float* op = ws_seg + (size_t)p * 128 + c * 8;
        *(float4*)op       = make_float4(acc[0], acc[1], acc[2], acc[3]);
        *(float4*)(op + 4) = make_float4(acc[4], acc[5], acc[6], acc[7]);
    }
}

// ------------------------------------------------------------------
// gate: rms-norm * sigmoid gate -> AG = [gated | h] bf16 [Mq,256]
// ------------------------------------------------------------------
__global__ void gate_kernel(const float* __restrict__ ws_seg, const float* __restrict__ ph,
                            const float* __restrict__ rms_w, const float* __restrict__ lin_w,
                            bf16_t* __restrict__ AG, int P_, int Mq)
{
    int tid = threadIdx.x;
    int g = tid >> 4, s = tid & 15;
    int p = blockIdx.x * 16 + g;
    if (p >= Mq) return;
    int cb = s * 8;
    if (p >= P_) {
        bf16x8 z = {};
        *(bf16x8*)(AG + (size_t)p * 256 + cb) = z;
        *(bf16x8*)(AG + (size_t)p * 256 + 128 + cb) = z;
        return;
    }
    const float* wp = ws_seg + (size_t)p * 128 + cb;
    float4 a = *(const float4*)wp, b = *(const float4*)(wp + 4);
    float wsv[8] = {a.x, a.y, a.z, a.w, b.x, b.y, b.z, b.w};
    float ss = 0.f;
#pragma unroll
    for (int j = 0; j < 8; ++j) ss += wsv[j] * wsv[j];
    ss += __shfl_xor(ss, 1); ss += __shfl_xor(ss, 2); ss += __shfl_xor(ss, 4); ss += __shfl_xor(ss, 8);
    float scale = rsqrtf(ss * (1.f / 128.f) + 1e-6f);
    const float* hp = ph + (size_t)p * 128 + cb;
    float4 ha = *(const float4*)hp, hb = *(const float4*)(hp + 4);
    float hv[8] = {ha.x, ha.y, ha.z, ha.w, hb.x, hb.y, hb.z, hb.w};
    bf16x8 gv, hvb;
#pragma unroll
    for (int j = 0; j < 8; ++j) {
        int c = cb + j;
        float rv = wsv[j] * scale * rms_w[c];
        gv[j] = (bf16_t)(rv * sigmoidf_(wsv[j] * lin_w[c]));
        hvb[j] = (bf16_t)hv[j];
    }
    *(bf16x8*)(AG + (size_t)p * 256 + cb) = gv;
    *(bf16x8*)(AG + (size_t)p * 256 + 128 + cb) = hvb;
}

// ------------------------------------------------------------------
// gru+ln pointwise: read G768 [Mq,768] fp32 (gi|gh), h=ph fp32;
// compute h_new, LayerNorm -> LNb bf16 [Mq,128]
// ------------------------------------------------------------------
__global__ void gru_ln_kernel(const float* __restrict__ G768, const float* __restrict__ ph,
                              const float* __restrict__ ln_g, const float* __restrict__ ln_b,
                              bf16_t* __restrict__ LNb, int P_, int Mq)
{
    int tid = threadIdx.x;
    int g = tid >> 4, s = tid & 15;
    int p = blockIdx.x * 16 + g;
    if (p >= Mq) return;
    int cb = s * 8;
    if (p >= P_) {
        bf16x8 z = {};
        *(bf16x8*)(LNb + (size_t)p * 128 + cb) = z;
        return;
    }
    const float* G = G768 + (size_t)p * 768;
    float ir[8], iz[8], in_[8], hr[8], hz[8], hn_[8], hv[8];
#pragma unroll
    for (int q = 0; q < 2; ++q) {
        float4 v;
        v = *(const float4*)(G + cb + q * 4);        ir[q*4]=v.x; ir[q*4+1]=v.y; ir[q*4+2]=v.z; ir[q*4+3]=v.w;
        v = *(const float4*)(G + 128 + cb + q * 4);  iz[q*4]=v.x; iz[q*4+1]=v.y; iz[q*4+2]=v.z; iz[q*4+3]=v.w;
        v = *(const float4*)(G + 256 + cb + q * 4);  in_[q*4]=v.x; in_[q*4+1]=v.y; in_[q*4+2]=v.z; in_[q*4+3]=v.w;
        v = *(const float4*)(G + 384 + cb + q * 4);  hr[q*4]=v.x; hr[q*4+1]=v.y; hr[q*4+2]=v.z; hr[q*4+3]=v.w;
        v = *(const float4*)(G + 512 + cb + q * 4);  hz[q*4]=v.x; hz[q*4+1]=v.y; hz[q*4+2]=v.z; hz[q*4+3]=v.w;
        v = *(const float4*)(G + 640 + cb + q * 4);  hn_[q*4]=v.x; hn_[q*4+1]=v.y; hn_[q*4+2]=v.z; hn_[q*4+3]=v.w;
        v = *(const float4*)(ph + (size_t)p * 128 + cb + q * 4);
        hv[q*4]=v.x; hv[q*4+1]=v.y; hv[q*4+2]=v.z; hv[q*4+3]=v.w;
    }
    float hn[8];
    float sm = 0.f, sq = 0.f;
#pragma unroll
    for (int j = 0; j < 8; ++j) {
        float r = sigmoidf_(ir[j] + hr[j]);
        float z = sigmoidf_(iz[j] + hz[j]);
        float n = tanhf(in_[j] + r * hn_[j]);
        hn[j] = (1.f - z) * n + z * hv[j];
        sm += hn[j]; sq += hn[j] * hn[j];
    }
    sm += __shfl_xor(sm, 1); sm += __shfl_xor(sm, 2); sm += __shfl_xor(sm, 4); sm += __shfl_xor(sm, 8);
    sq += __shfl_xor(sq, 1); sq += __shfl_xor(sq, 2); sq += __shfl_xor(sq, 4); sq += __shfl_xor(sq, 8);
    float mu = sm * (1.f / 128.f);
    float var = sq * (1.f / 128.f) - mu * mu;
    float iv = rsqrtf(var + 1e-5f);
    bf16x8 o;
#pragma unroll
    for (int j = 0; j < 8; ++j) {
        int c = cb + j;
        o[j] = (bf16_t)((hn[j] - mu) * iv * ln_g[c] + ln_b[c]);
    }
    *(bf16x8*)(LNb + (size_t)p * 128 + cb) = o;
}

// ------------------------------------------------------------------
extern "C" void kernel_launch(void* const* d_in, const int* in_sizes, int n_in,
                              void* d_out, int out_size, void* d_ws, size_t ws_size,
                              hipStream_t stream)
{
    const float* nh      = (const float*)d_in[0];
    const float* energy  = (const float*)d_in[1];
    const float* eta     = (const float*)d_in[2];
    const float* phi     = (const float*)d_in[3];
    const float* layer   = (const float*)d_in[4];
    const float* eta_l   = (const float*)d_in[5];
    const float* phi_l   = (const float*)d_in[6];
    const float* ene_l   = (const float*)d_in[7];
    const float* track   = (const float*)d_in[8];
    const float* ph      = (const float*)d_in[9];
    const float* grep    = (const float*)d_in[10];
    const int*   esrc    = (const int*)d_in[11];
    const int*   edst    = (const int*)d_in[12];
    const float* W_key   = (const float*)d_in[13];
    const float* b_key   = (const float*)d_in[14];
    const float* W_val   = (const float*)d_in[15];
    const float* b_val   = (const float*)d_in[16];
    const float* W_q     = (const float*)d_in[17];
    const float* b_q     = (const float*)d_in[18];
    const float* W_ih    = (const float*)d_in[19];
    const float* b_ih    = (const float*)d_in[20];
    const float* W_hh    = (const float*)d_in[21];
    const float* b_hh    = (const float*)d_in[22];
    const float* ln_g    = (const float*)d_in[23];
    const float* ln_b    = (const float*)d_in[24];
    const float* W1      = (const float*)d_in[25];
    const float* b1      = (const float*)d_in[26];
    const float* W2      = (const float*)d_in[27];
    const float* b2      = (const float*)d_in[28];
    const float* rms_w   = (const float*)d_in[29];
    const float* lin_w   = (const float*)d_in[30];

    const int N = in_sizes[1];
    const int P = in_sizes[9] / 128;
    const int E = in_sizes[11];
    const int Mpad = ((N + 127) / 128) * 128;   // 100096
    const int Mq   = ((P + 127) / 128) * 128;   // 10112

    // workspace layout (byte offsets, 256B aligned)
    char* base = (char*)d_ws;
    size_t off = 0;
    auto alloc = [&](size_t bytes) { void* p = base + off; off = (off + bytes + 255) & ~(size_t)255; return p; };
    bf16_t* Abf   = (bf16_t*)alloc((size_t)Mpad * 288 * 2);   // 57.6 MB
    bf16_t* Aq    = (bf16_t*)alloc((size_t)Mq * 384 * 2);     // 7.8 MB
    bf16_t* WbfT  = (bf16_t*)alloc(256 * 288 * 2);
    bf16_t* WqT   = (bf16_t*)alloc(128 * 384 * 2);
    float*  bpn   = (float*)alloc(256 * 4);
    float*  bpq   = (float*)alloc(128 * 4);
    bf16_t* Kb    = (bf16_t*)alloc((size_t)Mpad * 128 * 2);
    bf16_t* Vb    = (bf16_t*)alloc((size_t)Mpad * 128 * 2);
    bf16_t* Qb    = (bf16_t*)alloc((size_t)Mq * 128 * 2);
    float*  ws_seg= (float*)alloc((size_t)P * 128 * 4);
    // cnt and cur MUST be contiguous: zero_ints(cnt, 2*P) covers both.
    int*    cnt   = (int*)alloc((size_t)(2 * P) * 4);
    int*    cur   = cnt + P;
    int*    offb  = (int*)alloc((size_t)(P + 1) * 4);
    int*    csrc  = (int*)alloc((size_t)E * 4);   // CSR: src node ids
    // node-update buffers
    bf16_t* AG    = (bf16_t*)alloc((size_t)Mq * 256 * 2);     // [gated|h]
    bf16_t* BTg   = (bf16_t*)alloc(768 * 256 * 2);
    bf16_t* W1Tp  = (bf16_t*)alloc(128 * 128 * 2);
    bf16_t* W2Tp  = (bf16_t*)alloc(128 * 128 * 2);
    float*  bgru  = (float*)alloc(768 * 4);
    float*  b1p   = (float*)alloc(128 * 4);
    // Aliased (stream-ordered reuse of dead regions):
    float*  G768  = (float*)Abf;          // [Mq,768] fp32 in Abf (dead after gemm<0>)
    bf16_t* LNb   = Aq;                   // [Mq,128] bf16 in Aq (dead after gemm<1>)
    bf16_t* M1    = Aq + (size_t)Mq * 128;

    // 1. weight prep + input conversion
    {
        int total = 256 * 288 + 128 * 384 + 256 + 128;
        prep_kernel<<<(total + THREADS - 1) / THREADS, THREADS, 0, stream>>>(
            W_key, W_val, W_q, b_key, b_val, b_q, WbfT, WqT, bpn, bpq);
        int total2 = 768 * 256 + 128 * 128 + 128 * 128 + 768 + 128;
        prep2_kernel<<<(total2 + THREADS - 1) / THREADS, THREADS, 0, stream>>>(
            W_ih, W_hh, b_ih, b_hh, W1, b1, W2, BTg, W1Tp, W2Tp, bgru, b1p);
        convertA_kernel<<<Mpad * 32 / THREADS, THREADS, 0, stream>>>(nh, Abf, N);
        skip_kernel<<<(Mpad + THREADS - 1) / THREADS, THREADS, 0, stream>>>(
            energy, eta, phi, layer, eta_l, phi_l, ene_l, track, Abf, N, Mpad);
        convertQ_kernel<<<Mq * 48 / THREADS, THREADS, 0, stream>>>(ph, grep, Aq, P);
    }
    // 2. MFMA GEMMs (keys/vals and q)
    mfma_gemm<0><<<dim3(2, Mpad / 128), THREADS, 0, stream>>>(
        Abf, WbfT, bpn, Kb, Vb, nullptr, 288, 0);
    mfma_gemm<1><<<dim3(1, Mq / 128), THREADS, 0, stream>>>(
        Aq, WqT, bpq, Qb, nullptr, nullptr, 384, 0);
    // 3. CSR build (src ids stored directly)
    zero_ints<<<(2 * P + THREADS - 1) / THREADS, THREADS, 0, stream>>>(cnt, 2 * P);
    hist_kernel<<<(E + THREADS - 1) / THREADS, THREADS, 0, stream>>>(edst, cnt, E);
    scan_kernel<<<1, 1024, 0, stream>>>(cnt, offb, P);
    fill_src_kernel<<<(E + THREADS - 1) / THREADS, THREADS, 0, stream>>>(
        edst, esrc, offb, cur, csrc, E);
    // 4. fused attention + gather
    edge_kernel<<<(P + 3) / 4, THREADS, 0, stream>>>(offb, csrc, Kb, Vb, Qb, ws_seg, P);
    // 5. node update: gate -> GRU GEMM -> pointwise+LN -> MLP1 -> MLP2+residual
    gate_kernel<<<Mq / 16, THREADS, 0, stream>>>(ws_seg, ph, rms_w, lin_w, AG, P, Mq);
    mfma_gemm<2><<<dim3(6, Mq / 128), THREADS, 0, stream>>>(
        AG, BTg, bgru, G768, nullptr, nullptr, 256, 0);
    gru_ln_kernel<<<Mq / 16, THREADS, 0, stream>>>(G768, ph, ln_g, ln_b, LNb, P, Mq);
    mfma_gemm<3><<<dim3(1, Mq / 128), THREADS, 0, stream>>>(
        LNb, W1Tp, b1p, M1, nullptr, nullptr, 128, 0);
    mfma_gemm<4><<<dim3(1, Mq / 128), THREADS, 0, stream>>>(
        M1, W2Tp, b2, d_out, nullptr, ph, 128, P);
}

// Round 6
// 261.692 us; speedup vs baseline: 2.5394x; 1.0124x over previous
//
#include <hip/hip_runtime.h>
#include <hip/hip_bf16.h>
#include <math.h>

#define THREADS 256

typedef __bf16 bf16_t;
typedef __bf16 bf16x8 __attribute__((ext_vector_type(8)));
typedef float f32x4 __attribute__((ext_vector_type(4)));

__device__ __forceinline__ float sigmoidf_(float x) { return 1.f / (1.f + expf(-x)); }

__device__ __forceinline__ void gload_lds16(const void* g, void* l) {
    __builtin_amdgcn_global_load_lds((const __attribute__((address_space(1))) void*)g,
                                     (__attribute__((address_space(3))) void*)l, 16, 0, 0);
}

__device__ __forceinline__ bf16x8 cvt8(float4 a, float4 b) {
    bf16x8 v;
    v[0] = (bf16_t)a.x; v[1] = (bf16_t)a.y; v[2] = (bf16_t)a.z; v[3] = (bf16_t)a.w;
    v[4] = (bf16_t)b.x; v[5] = (bf16_t)b.y; v[6] = (bf16_t)b.z; v[7] = (bf16_t)b.w;
    return v;
}

// ------------------------------------------------------------------
// prep: pack transposed bf16 weights for key/val/q GEMMs.
// WbfT [256][288], WqT [128][384], bpn[256], bpq[128]
// ------------------------------------------------------------------
__global__ void prep_kernel(const float* __restrict__ W_key, const float* __restrict__ W_val,
                            const float* __restrict__ W_q, const float* __restrict__ b_key,
                            const float* __restrict__ b_val, const float* __restrict__ b_q,
                            bf16_t* __restrict__ WbfT, bf16_t* __restrict__ WqT,
                            float* __restrict__ bpn, float* __restrict__ bpq)
{
    int i = blockIdx.x * THREADS + threadIdx.x;
    const int NW = 256 * 288, NQ = 128 * 384;
    if (i < NW) {
        int c = i / 288, k = i - c * 288;
        float v = 0.f;
        if (k < 283) {
            if (c < 100) v = W_key[k * 100 + c];
            else if (c >= 128 && c < 256) v = W_val[k * 128 + (c - 128)];
        }
        WbfT[i] = (bf16_t)v;
    } else if (i < NW + NQ) {
        int j = i - NW;
        int c = j / 384, k = j - c * 384;
        WqT[j] = (bf16_t)((c < 100) ? W_q[k * 100 + c] : 0.f);
    } else if (i < NW + NQ + 256) {
        int c = i - NW - NQ;
        bpn[c] = (c < 100) ? b_key[c] : ((c >= 128 && c < 256) ? b_val[c - 128] : 0.f);
    } else if (i < NW + NQ + 256 + 128) {
        int c = i - NW - NQ - 256;
        bpq[c] = (c < 100) ? b_q[c] : 0.f;
    }
}

// ------------------------------------------------------------------
// prep2: pack GRU block-diag BTg [768][256], W1Tp [128][128],
// W2Tp [128][128], bgru[768], b1p[128]
// ------------------------------------------------------------------
__global__ void prep2_kernel(const float* __restrict__ W_ih, const float* __restrict__ W_hh,
                             const float* __restrict__ b_ih, const float* __restrict__ b_hh,
                             const float* __restrict__ W1, const float* __restrict__ b1,
                             const float* __restrict__ W2,
                             bf16_t* __restrict__ BTg, bf16_t* __restrict__ W1Tp,
                             bf16_t* __restrict__ W2Tp, float* __restrict__ bgru,
                             float* __restrict__ b1p)
{
    int i = blockIdx.x * THREADS + threadIdx.x;
    const int NG = 768 * 256, N1 = 128 * 128, N2 = 128 * 128;
    if (i < NG) {
        int c = i >> 8, k = i & 255;
        float v = 0.f;
        if (c < 384) { if (k < 128) v = W_ih[k * 384 + c]; }
        else         { if (k >= 128) v = W_hh[(k - 128) * 384 + (c - 384)]; }
        BTg[i] = (bf16_t)v;
    } else if (i < NG + N1) {
        int j = i - NG; int c = j >> 7, k = j & 127;
        W1Tp[j] = (bf16_t)((c < 64) ? W1[k * 64 + c] : 0.f);
    } else if (i < NG + N1 + N2) {
        int j = i - NG - N1; int c = j >> 7, k = j & 127;
        W2Tp[j] = (bf16_t)((k < 64) ? W2[k * 128 + c] : 0.f);
    } else if (i < NG + N1 + N2 + 768) {
        int c = i - NG - N1 - N2;
        bgru[c] = (c < 384) ? b_ih[c] : b_hh[c - 384];
    } else if (i < NG + N1 + N2 + 768 + 128) {
        int c = i - NG - N1 - N2 - 768;
        b1p[c] = (c < 64) ? b1[c] : 0.f;
    }
}

// skip features -> skipb bf16 [Mpad,32] (27 real + 5 zero; pad rows zero)
__global__ void skip_kernel(const float* __restrict__ energy, const float* __restrict__ eta,
                            const float* __restrict__ phi, const float* __restrict__ layer,
                            const float* __restrict__ eta_l, const float* __restrict__ phi_l,
                            const float* __restrict__ ene_l, const float* __restrict__ track,
                            bf16_t* __restrict__ skipb, int N_, int Mpad)
{
    int n = blockIdx.x * THREADS + threadIdx.x;
    if (n >= Mpad) return;
    float o[32];
#pragma unroll
    for (int j = 0; j < 32; ++j) o[j] = 0.f;
    if (n < N_) {
        o[0] = (logf(energy[n]) - 4.0f) * 0.5f;
        o[1] = eta[n] * (1.f / 1.5f);
        o[2] = phi[n];
        o[3] = layer[n];
#pragma unroll
        for (int j = 0; j < 6; ++j) o[4 + j]  = eta_l[n * 6 + j] * (1.f / 1.5f);
#pragma unroll
        for (int j = 0; j < 6; ++j) o[10 + j] = phi_l[n * 6 + j];
#pragma unroll
        for (int j = 0; j < 6; ++j) o[16 + j] = ene_l[n * 6 + j];
#pragma unroll
        for (int j = 0; j < 5; ++j) o[22 + j] = track[n * 5 + j];
    }
    bf16_t* dst = skipb + (size_t)n * 32;
#pragma unroll
    for (int g = 0; g < 4; ++g) {
        bf16x8 v;
#pragma unroll
        for (int j = 0; j < 8; ++j) v[j] = (bf16_t)o[g * 8 + j];
        *(bf16x8*)(dst + g * 8) = v;
    }
}

// ------------------------------------------------------------------
// bf16 MFMA GEMM, m97 structure: 128x128 tile, BK=32, 4 waves, 64x64/wave.
// A-staging fuses fp32->bf16 conversion (reg-staged) where needed:
// MODE 0: A = nh fp32 [.,256] | skipb bf16 [.,32]; K=288; out KVb bf16 ldc256
// MODE 1: A = ph fp32 [.,128] | grep fp32 [.,256]; K=384; out Qb bf16
// MODE 2: A bf16 stride K; fp32 out ldc=768 (GRU gi|gh)
// MODE 3: A bf16; bf16 out + relu (MLP1)
// MODE 4: A bf16; fp32 out = acc+bias+resid, guarded row<Mlimit (MLP2+res)
// Nrows = valid A rows (gm >= Nrows staged as zeros for fp32 paths)
// ------------------------------------------------------------------
template <int MODE>
__global__ __launch_bounds__(256) void mfma_gemm(
    const void* __restrict__ A0, const void* __restrict__ A1,
    const bf16_t* __restrict__ BT, const float* __restrict__ bias,
    void* __restrict__ out0v, const float* __restrict__ resid,
    int K, int Mlimit, int Nrows)
{
    __shared__ short AsS[128 * 32];  // [row][k] bf16, 64B rows
    __shared__ short BsS[128 * 32];  // [col][k]
    int tid = threadIdx.x;
    int lane = tid & 63, w = tid >> 6;
    int la = lane & 15, hi = lane >> 4;
    int m0 = (w & 1) * 64, n0 = (w >> 1) * 64;
    int row0 = blockIdx.y * 128, col0 = blockIdx.x * 128;

    f32x4 zero4 = {0.f, 0.f, 0.f, 0.f};
    f32x4 acc[4][4];
#pragma unroll
    for (int i = 0; i < 4; ++i)
#pragma unroll
        for (int j = 0; j < 4; ++j) acc[i][j] = zero4;

    for (int kt = 0; kt < K; kt += 32) {
#pragma unroll
        for (int it = 0; it < 2; ++it) {
            int c = tid + it * 256;
            int r = c >> 2, kc = c & 3;
            int gm = row0 + r, gk = kt + kc * 8;
            if (MODE == 0) {
                if (gk < 256) {  // uniform per kt (tiles 32-aligned)
                    bf16x8 v = {};
                    if (gm < Nrows) {
                        const float* src = (const float*)A0 + (size_t)gm * 256 + gk;
                        v = cvt8(*(const float4*)src, *(const float4*)(src + 4));
                    }
                    *(bf16x8*)((short*)AsS + (size_t)c * 8) = v;
                } else {
                    gload_lds16((const bf16_t*)A1 + (size_t)gm * 32 + (gk - 256), AsS + c * 8);
                }
            } else if (MODE == 1) {
                bf16x8 v = {};
                if (gm < Nrows) {
                    const float* src = (gk < 128)
                        ? ((const float*)A0 + (size_t)gm * 128 + gk)
                        : ((const float*)A1 + (size_t)gm * 256 + (gk - 128));
                    v = cvt8(*(const float4*)src, *(const float4*)(src + 4));
                }
                *(bf16x8*)((short*)AsS + (size_t)c * 8) = v;
            } else {
                gload_lds16((const bf16_t*)A0 + (size_t)gm * K + gk, AsS + c * 8);
            }
            gload_lds16(BT + (size_t)(col0 + r) * K + kt + kc * 8, BsS + c * 8);
        }
        __syncthreads();
        bf16x8 a[4], b[4];
#pragma unroll
        for (int i = 0; i < 4; ++i)
            a[i] = *(const bf16x8*)(AsS + (m0 + i * 16 + la) * 32 + hi * 8);
#pragma unroll
        for (int j = 0; j < 4; ++j)
            b[j] = *(const bf16x8*)(BsS + (n0 + j * 16 + la) * 32 + hi * 8);
#pragma unroll
        for (int i = 0; i < 4; ++i)
#pragma unroll
            for (int j = 0; j < 4; ++j)
                acc[i][j] = __builtin_amdgcn_mfma_f32_16x16x32_bf16(a[i], b[j], acc[i][j], 0, 0, 0);
        __syncthreads();
    }

#pragma unroll
    for (int i = 0; i < 4; ++i) {
#pragma unroll
        for (int j = 0; j < 4; ++j) {
            int col = col0 + n0 + j * 16 + la;
            float bb = bias[col];
#pragma unroll
            for (int r = 0; r < 4; ++r) {
                int row = row0 + m0 + i * 16 + hi * 4 + r;
                float v = acc[i][j][r] + bb;
                if (MODE == 0) {
                    ((bf16_t*)out0v)[(size_t)row * 256 + col] = (bf16_t)v;  // KVb interleaved
                } else if (MODE == 1) {
                    ((bf16_t*)out0v)[(size_t)row * 128 + col] = (bf16_t)v;
                } else if (MODE == 2) {
                    ((float*)out0v)[(size_t)row * 768 + col] = v;
                } else if (MODE == 3) {
                    ((bf16_t*)out0v)[(size_t)row * 128 + col] = (bf16_t)fmaxf(v, 0.f);
                } else {  // MODE 4
                    if (row < Mlimit)
                        ((float*)out0v)[(size_t)row * 128 + col] = v + resid[(size_t)row * 128 + col];
                }
            }
        }
    }
}

// ------------------------------------------------------------------
// CSR build
// ------------------------------------------------------------------
__global__ void zero_ints(int* __restrict__ p, int n)
{
    int i = blockIdx.x * THREADS + threadIdx.x;
    if (i < n) p[i] = 0;
}

__global__ void hist_kernel(const int* __restrict__ dst, int* __restrict__ cnt, int E_)
{
    int i = blockIdx.x * THREADS + threadIdx.x;
    if (i < E_) atomicAdd(&cnt[dst[i]], 1);
}

// single-block shfl-based exclusive scan; 1024 threads x 10 elems covers P+1<=10240
__global__ void scan_kernel(const int* __restrict__ cnt, int* __restrict__ offb, int P_)
{
    __shared__ int wsum[16];
    int tid = threadIdx.x;
    int lane = tid & 63, w = tid >> 6;
    int base = tid * 10;
    int c[10];
    int s = 0;
#pragma unroll
    for (int j = 0; j < 10; ++j) {
        int i = base + j;
        c[j] = (i < P_) ? cnt[i] : 0;
        s += c[j];
    }
    int pre = s;
    for (int o = 1; o < 64; o <<= 1) {
        int t = __shfl_up(pre, o);
        if (lane >= o) pre += t;
    }
    if (lane == 63) wsum[w] = pre;
    __syncthreads();
    if (w == 0 && lane < 16) {
        int v = wsum[lane];
        for (int o = 1; o < 16; o <<= 1) {
            int t = __shfl_up(v, o, 16);
            if (lane >= o) v += t;
        }
        wsum[lane] = v;
    }
    __syncthreads();
    int waveoff = (w == 0) ? 0 : wsum[w - 1];
    int run = waveoff + pre - s;
#pragma unroll
    for (int j = 0; j < 10; ++j) {
        int i = base + j;
        if (i <= P_) offb[i] = run;
        run += c[j];
    }
}

// fill: store SRC NODE ID directly
__global__ void fill_src_kernel(const int* __restrict__ dst, const int* __restrict__ src,
                                const int* __restrict__ offb, int* __restrict__ cur,
                                int* __restrict__ csrc, int E_)
{
    int i = blockIdx.x * THREADS + threadIdx.x;
    if (i < E_) {
        int d = dst[i];
        int pos = atomicAdd(&cur[d], 1);
        csrc[offb[d] + pos] = src[i];
    }
}

// ------------------------------------------------------------------
// fused attention+gather: 1 wave/particle, 4 particles/block.
// lane = (g=lane>>4 edge-group, c=lane&15 col-chunk). KVb row: K cols 0..127,
// V cols 128..255. 4-edge unroll -> 8 x 16B loads in flight per group.
// ------------------------------------------------------------------
__global__ __launch_bounds__(256) void edge_kernel(
    const int* __restrict__ offb, const int* __restrict__ csrc,
    const bf16_t* __restrict__ KVb, const bf16_t* __restrict__ Qb,
    float* __restrict__ ws_seg, int P_)
{
    int tid = threadIdx.x;
    int p = blockIdx.x * 4 + (tid >> 6);
    if (p >= P_) return;
    int lane = tid & 63;
    int c = lane & 15, g = lane >> 4;

    bf16x8 q8 = *(const bf16x8*)(Qb + (size_t)p * 128 + c * 8);
    float qf[8];
#pragma unroll
    for (int j = 0; j < 8; ++j) qf[j] = (float)q8[j];

    int s0 = offb[p], e0 = offb[p + 1];
    float acc[8] = {};

    int i = s0 + g;
    for (; i + 12 < e0; i += 16) {
        int n0 = csrc[i], n1 = csrc[i + 4], n2 = csrc[i + 8], n3 = csrc[i + 12];
        const bf16_t* b0 = KVb + (size_t)n0 * 256 + c * 8;
        const bf16_t* b1 = KVb + (size_t)n1 * 256 + c * 8;
        const bf16_t* b2 = KVb + (size_t)n2 * 256 + c * 8;
        const bf16_t* b3 = KVb + (size_t)n3 * 256 + c * 8;
        bf16x8 k0 = *(const bf16x8*)b0, v0 = *(const bf16x8*)(b0 + 128);
        bf16x8 k1 = *(const bf16x8*)b1, v1 = *(const bf16x8*)(b1 + 128);
        bf16x8 k2 = *(const bf16x8*)b2, v2 = *(const bf16x8*)(b2 + 128);
        bf16x8 k3 = *(const bf16x8*)b3, v3 = *(const bf16x8*)(b3 + 128);
        float d0 = 0.f, d1 = 0.f, d2 = 0.f, d3 = 0.f;
#pragma unroll
        for (int j = 0; j < 8; ++j) {
            d0 += qf[j] * (float)k0[j]; d1 += qf[j] * (float)k1[j];
            d2 += qf[j] * (float)k2[j]; d3 += qf[j] * (float)k3[j];
        }
        d0 += __shfl_xor(d0, 1); d1 += __shfl_xor(d1, 1); d2 += __shfl_xor(d2, 1); d3 += __shfl_xor(d3, 1);
        d0 += __shfl_xor(d0, 2); d1 += __shfl_xor(d1, 2); d2 += __shfl_xor(d2, 2); d3 += __shfl_xor(d3, 2);
        d0 += __shfl_xor(d0, 4); d1 += __shfl_xor(d1, 4); d2 += __shfl_xor(d2, 4); d3 += __shfl_xor(d3, 4);
        d0 += __shfl_xor(d0, 8); d1 += __shfl_xor(d1, 8); d2 += __shfl_xor(d2, 8); d3 += __shfl_xor(d3, 8);
        float a0 = fmaxf(d0 * 0.1f, 0.f), a1 = fmaxf(d1 * 0.1f, 0.f);
        float a2 = fmaxf(d2 * 0.1f, 0.f), a3 = fmaxf(d3 * 0.1f, 0.f);
#pragma unroll
        for (int j = 0; j < 8; ++j)
            acc[j] += a0 * (float)v0[j] + a1 * (float)v1[j]
                    + a2 * (float)v2[j] + a3 * (float)v3[j];
    }
    for (; i < e0; i += 4) {
        int nA = csrc[i];
        const bf16_t* bA = KVb + (size_t)nA * 256 + c * 8;
        bf16x8 kA = *(const bf16x8*)bA;
        bf16x8 vA = *(const bf16x8*)(bA + 128);
        float dA = 0.f;
#pragma unroll
        for (int j = 0; j < 8; ++j) dA += qf[j] * (float)kA[j];
        dA += __shfl_xor(dA, 1);
        dA += __shfl_xor(dA, 2);
        dA += __shfl_xor(dA, 4);
        dA += __shfl_xor(dA, 8);
        float aA = fmaxf(dA * 0.1f, 0.f);
#pragma unroll
        for (int j = 0; j < 8; ++j) acc[j] += aA * (float)vA[j];
    }

    // reduce across the 4 edge-groups (lane bits 4,5)
#pragma unroll
    for (int j = 0; j < 8; ++j) {
        acc[j] += __shfl_xor(acc[j], 16);
        acc[j] += __shfl_xor(acc[j], 32);
    }
    if (g == 0) {
        float* op = ws_seg + (size_t)p * 128 + c * 8;
        *(float4*)op       = make_float4(acc[0], acc[1], acc[2], acc[3]);
        *(float4*)(op + 4) = make_float4(acc[4], acc[5], acc[6], acc[7]);
    }
}

// ------------------------------------------------------------------
// gate: rms-norm * sigmoid gate -> AG = [gated | h] bf16 [Mq,256]
// ------------------------------------------------------------------
__global__ void gate_kernel(const float* __restrict__ ws_seg, const float* __restrict__ ph,
                            const float* __restrict__ rms_w, const float* __restrict__ lin_w,
                            bf16_t* __restrict__ AG, int P_, int Mq)
{
    int tid = threadIdx.x;
    int g = tid >> 4, s = tid & 15;
    int p = blockIdx.x * 16 + g;
    if (p >= Mq) return;
    int cb = s * 8;
    if (p >= P_) {
        bf16x8 z = {};
        *(bf16x8*)(AG + (size_t)p * 256 + cb) = z;
        *(bf16x8*)(AG + (size_t)p * 256 + 128 + cb) = z;
        return;
    }
    const float* wp = ws_seg + (size_t)p * 128 + cb;
    float4 a = *(const float4*)wp, b = *(const float4*)(wp + 4);
    float wsv[8] = {a.x, a.y, a.z, a.w, b.x, b.y, b.z, b.w};
    float ss = 0.f;
#pragma unroll
    for (int j = 0; j < 8; ++j) ss += wsv[j] * wsv[j];
    ss += __shfl_xor(ss, 1); ss += __shfl_xor(ss, 2); ss += __shfl_xor(ss, 4); ss += __shfl_xor(ss, 8);
    float scale = rsqrtf(ss * (1.f / 128.f) + 1e-6f);
    const float* hp = ph + (size_t)p * 128 + cb;
    float4 ha = *(const float4*)hp, hb = *(const float4*)(hp + 4);
    float hv[8] = {ha.x, ha.y, ha.z, ha.w, hb.x, hb.y, hb.z, hb.w};
    bf16x8 gv, hvb;
#pragma unroll
    for (int j = 0; j < 8; ++j) {
        int c = cb + j;
        float rv = wsv[j] * scale * rms_w[c];
        gv[j] = (bf16_t)(rv * sigmoidf_(wsv[j] * lin_w[c]));
        hvb[j] = (bf16_t)hv[j];
    }
    *(bf16x8*)(AG + (size_t)p * 256 + cb) = gv;
    *(bf16x8*)(AG + (size_t)p * 256 + 128 + cb) = hvb;
}

// ------------------------------------------------------------------
// gru+ln pointwise: read G768 [Mq,768] fp32 (gi|gh), h=ph fp32;
// compute h_new, LayerNorm -> LNb bf16 [Mq,128]
// ------------------------------------------------------------------
__global__ void gru_ln_kernel(const float* __restrict__ G768, const float* __restrict__ ph,
                              const float* __restrict__ ln_g, const float* __restrict__ ln_b,
                              bf16_t* __restrict__ LNb, int P_, int Mq)
{
    int tid = threadIdx.x;
    int g = tid >> 4, s = tid & 15;
    int p = blockIdx.x * 16 + g;
    if (p >= Mq) return;
    int cb = s * 8;
    if (p >= P_) {
        bf16x8 z = {};
        *(bf16x8*)(LNb + (size_t)p * 128 + cb) = z;
        return;
    }
    const float* G = G768 + (size_t)p * 768;
    float ir[8], iz[8], in_[8], hr[8], hz[8], hn_[8], hv[8];
#pragma unroll
    for (int q = 0; q < 2; ++q) {
        float4 v;
        v = *(const float4*)(G + cb + q * 4);        ir[q*4]=v.x; ir[q*4+1]=v.y; ir[q*4+2]=v.z; ir[q*4+3]=v.w;
        v = *(const float4*)(G + 128 + cb + q * 4);  iz[q*4]=v.x; iz[q*4+1]=v.y; iz[q*4+2]=v.z; iz[q*4+3]=v.w;
        v = *(const float4*)(G + 256 + cb + q * 4);  in_[q*4]=v.x; in_[q*4+1]=v.y; in_[q*4+2]=v.z; in_[q*4+3]=v.w;
        v = *(const float4*)(G + 384 + cb + q * 4);  hr[q*4]=v.x; hr[q*4+1]=v.y; hr[q*4+2]=v.z; hr[q*4+3]=v.w;
        v = *(const float4*)(G + 512 + cb + q * 4);  hz[q*4]=v.x; hz[q*4+1]=v.y; hz[q*4+2]=v.z; hz[q*4+3]=v.w;
        v = *(const float4*)(G + 640 + cb + q * 4);  hn_[q*4]=v.x; hn_[q*4+1]=v.y; hn_[q*4+2]=v.z; hn_[q*4+3]=v.w;
        v = *(const float4*)(ph + (size_t)p * 128 + cb + q * 4);
        hv[q*4]=v.x; hv[q*4+1]=v.y; hv[q*4+2]=v.z; hv[q*4+3]=v.w;
    }
    float hn[8];
    float sm = 0.f, sq = 0.f;
#pragma unroll
    for (int j = 0; j < 8; ++j) {
        float r = sigmoidf_(ir[j] + hr[j]);
        float z = sigmoidf_(iz[j] + hz[j]);
        float n = tanhf(in_[j] + r * hn_[j]);
        hn[j] = (1.f - z) * n + z * hv[j];
        sm += hn[j]; sq += hn[j] * hn[j];
    }
    sm += __shfl_xor(sm, 1); sm += __shfl_xor(sm, 2); sm += __shfl_xor(sm, 4); sm += __shfl_xor(sm, 8);
    sq += __shfl_xor(sq, 1); sq += __shfl_xor(sq, 2); sq += __shfl_xor(sq, 4); sq += __shfl_xor(sq, 8);
    float mu = sm * (1.f / 128.f);
    float var = sq * (1.f / 128.f) - mu * mu;
    float iv = rsqrtf(var + 1e-5f);
    bf16x8 o;
#pragma unroll
    for (int j = 0; j < 8; ++j) {
        int c = cb + j;
        o[j] = (bf16_t)((hn[j] - mu) * iv * ln_g[c] + ln_b[c]);
    }
    *(bf16x8*)(LNb + (size_t)p * 128 + cb) = o;
}

// ------------------------------------------------------------------
extern "C" void kernel_launch(void* const* d_in, const int* in_sizes, int n_in,
                              void* d_out, int out_size, void* d_ws, size_t ws_size,
                              hipStream_t stream)
{
    const float* nh      = (const float*)d_in[0];
    const float* energy  = (const float*)d_in[1];
    const float* eta     = (const float*)d_in[2];
    const float* phi     = (const float*)d_in[3];
    const float* layer   = (const float*)d_in[4];
    const float* eta_l   = (const float*)d_in[5];
    const float* phi_l   = (const float*)d_in[6];
    const float* ene_l   = (const float*)d_in[7];
    const float* track   = (const float*)d_in[8];
    const float* ph      = (const float*)d_in[9];
    const float* grep    = (const float*)d_in[10];
    const int*   esrc    = (const int*)d_in[11];
    const int*   edst    = (const int*)d_in[12];
    const float* W_key   = (const float*)d_in[13];
    const float* b_key   = (const float*)d_in[14];
    const float* W_val   = (const float*)d_in[15];
    const float* b_val   = (const float*)d_in[16];
    const float* W_q     = (const float*)d_in[17];
    const float* b_q     = (const float*)d_in[18];
    const float* W_ih    = (const float*)d_in[19];
    const float* b_ih    = (const float*)d_in[20];
    const float* W_hh    = (const float*)d_in[21];
    const float* b_hh    = (const float*)d_in[22];
    const float* ln_g    = (const float*)d_in[23];
    const float* ln_b    = (const float*)d_in[24];
    const float* W1      = (const float*)d_in[25];
    const float* b1      = (const float*)d_in[26];
    const float* W2      = (const float*)d_in[27];
    const float* b2      = (const float*)d_in[28];
    const float* rms_w   = (const float*)d_in[29];
    const float* lin_w   = (const float*)d_in[30];

    const int N = in_sizes[1];
    const int P = in_sizes[9] / 128;
    const int E = in_sizes[11];
    const int Mpad = ((N + 127) / 128) * 128;   // 100096
    const int Mq   = ((P + 127) / 128) * 128;   // 10112

    // workspace layout (byte offsets, 256B aligned)
    char* base = (char*)d_ws;
    size_t off = 0;
    auto alloc = [&](size_t bytes) { void* p = base + off; off = (off + bytes + 255) & ~(size_t)255; return p; };
    bf16_t* skipb = (bf16_t*)alloc((size_t)Mpad * 32 * 2);    // 6.4 MB
    bf16_t* WbfT  = (bf16_t*)alloc(256 * 288 * 2);
    bf16_t* WqT   = (bf16_t*)alloc(128 * 384 * 2);
    float*  bpn   = (float*)alloc(256 * 4);
    float*  bpq   = (float*)alloc(128 * 4);
    bf16_t* KVb   = (bf16_t*)alloc((size_t)Mpad * 256 * 2);   // 51.2 MB interleaved K|V
    bf16_t* Qb    = (bf16_t*)alloc((size_t)Mq * 128 * 2);
    float*  ws_seg= (float*)alloc((size_t)P * 128 * 4);
    // cnt and cur MUST be contiguous: zero_ints(cnt, 2*P) covers both.
    int*    cnt   = (int*)alloc((size_t)(2 * P) * 4);
    int*    cur   = cnt + P;
    int*    offb  = (int*)alloc((size_t)(P + 1) * 4);
    int*    csrc  = (int*)alloc((size_t)E * 4);
    // node-update buffers
    bf16_t* AG    = (bf16_t*)alloc((size_t)Mq * 256 * 2);
    bf16_t* BTg   = (bf16_t*)alloc(768 * 256 * 2);
    bf16_t* W1Tp  = (bf16_t*)alloc(128 * 128 * 2);
    bf16_t* W2Tp  = (bf16_t*)alloc(128 * 128 * 2);
    float*  bgru  = (float*)alloc(768 * 4);
    float*  b1p   = (float*)alloc(128 * 4);
    float*  G768  = (float*)alloc((size_t)Mq * 768 * 4);      // 31 MB
    bf16_t* LNb   = (bf16_t*)alloc((size_t)Mq * 128 * 2);
    bf16_t* M1    = (bf16_t*)alloc((size_t)Mq * 128 * 2);

    // 1. weight prep + skip features
    {
        int total = 256 * 288 + 128 * 384 + 256 + 128;
        prep_kernel<<<(total + THREADS - 1) / THREADS, THREADS, 0, stream>>>(
            W_key, W_val, W_q, b_key, b_val, b_q, WbfT, WqT, bpn, bpq);
        int total2 = 768 * 256 + 128 * 128 + 128 * 128 + 768 + 128;
        prep2_kernel<<<(total2 + THREADS - 1) / THREADS, THREADS, 0, stream>>>(
            W_ih, W_hh, b_ih, b_hh, W1, b1, W2, BTg, W1Tp, W2Tp, bgru, b1p);
        skip_kernel<<<(Mpad + THREADS - 1) / THREADS, THREADS, 0, stream>>>(
            energy, eta, phi, layer, eta_l, phi_l, ene_l, track, skipb, N, Mpad);
    }
    // 2. MFMA GEMMs with fused fp32->bf16 A-staging
    mfma_gemm<0><<<dim3(2, Mpad / 128), THREADS, 0, stream>>>(
        nh, skipb, WbfT, bpn, KVb, nullptr, 288, 0, N);
    mfma_gemm<1><<<dim3(1, Mq / 128), THREADS, 0, stream>>>(
        ph, grep, WqT, bpq, Qb, nullptr, 384, 0, P);
    // 3. CSR build (src ids stored directly)
    zero_ints<<<(2 * P + THREADS - 1) / THREADS, THREADS, 0, stream>>>(cnt, 2 * P);
    hist_kernel<<<(E + THREADS - 1) / THREADS, THREADS, 0, stream>>>(edst, cnt, E);
    scan_kernel<<<1, 1024, 0, stream>>>(cnt, offb, P);
    fill_src_kernel<<<(E + THREADS - 1) / THREADS, THREADS, 0, stream>>>(
        edst, esrc, offb, cur, csrc, E);
    // 4. fused attention + gather
    edge_kernel<<<(P + 3) / 4, THREADS, 0, stream>>>(offb, csrc, KVb, Qb, ws_seg, P);
    // 5. node update: gate -> GRU GEMM -> pointwise+LN -> MLP1 -> MLP2+residual
    gate_kernel<<<Mq / 16, THREADS, 0, stream>>>(ws_seg, ph, rms_w, lin_w, AG, P, Mq);
    mfma_gemm<2><<<dim3(6, Mq / 128), THREADS, 0, stream>>>(
        AG, nullptr, BTg, bgru, G768, nullptr, 256, 0, Mq);
    gru_ln_kernel<<<Mq / 16, THREADS, 0, stream>>>(G768, ph, ln_g, ln_b, LNb, P, Mq);
    mfma_gemm<3><<<dim3(1, Mq / 128), THREADS, 0, stream>>>(
        LNb, nullptr, W1Tp, b1p, M1, nullptr, 128, 0, Mq);
    mfma_gemm<4><<<dim3(1, Mq / 128), THREADS, 0, stream>>>(
        M1, nullptr, W2Tp, b2, d_out, ph, 128, P, Mq);
}